// Round 18
// baseline (70.199 us; speedup 1.0000x reference)
//
#include <hip/hip_runtime.h>

#define DEV __device__ __forceinline__

typedef unsigned u32;
typedef u32 u32x2 __attribute__((ext_vector_type(2)));
typedef _Float16 f16;
typedef f16   f16x8 __attribute__((ext_vector_type(8)));
typedef float f32x4 __attribute__((ext_vector_type(4)));

// ---------- DPP helpers ----------
template<int CTRL>
DEV int dpp_full(int src) {
    return __builtin_amdgcn_update_dpp(src, src, CTRL, 0xF, 0xF, false);
}
template<int CTRL, int RM, int BM>
DEV int dpp_masked(int old, int src) {
    return __builtin_amdgcn_update_dpp(old, src, CTRL, RM, BM, false);
}

// ---------- cross-lane xor-shuffle (r7-proven mix) ----------
template<int B>
DEV float lshfl(float x, bool px) {
    int xi = __float_as_int(x);
    if constexpr (B == 0) {
        return __int_as_float(dpp_full<0xB1>(xi));          // xor1
    } else if constexpr (B == 1) {
        return __int_as_float(dpp_full<0x4E>(xi));          // xor2
    } else if constexpr (B == 2) {
        return __int_as_float(__builtin_amdgcn_ds_swizzle(xi, 0x101F)); // xor4
    } else if constexpr (B == 3) {
        return __int_as_float(dpp_full<0x128>(xi));         // xor8
    } else if constexpr (B == 4) {
        return __int_as_float(__builtin_amdgcn_ds_swizzle(xi, 0x401F)); // xor16
    } else {
        u32x2 r = __builtin_amdgcn_permlane32_swap((u32)xi, (u32)xi, false, false);
        return __int_as_float((int)(px ? r.x : r.y));
    }
}

DEV bool probe32(int lane) {
    u32 p = (u32)((lane >> 5) & 1);
    u32x2 r = __builtin_amdgcn_permlane32_swap(p, p, false, false);
    return r.x == (p ^ 1u);
}

// ---------- complex pair primitives (fp32) ----------
DEV void rx_pair(float& r0, float& i0, float& r1, float& i1, float c, float s) {
    float nr0 = fmaf(c, r0,  s * i1);
    float ni0 = fmaf(c, i0, -s * r1);
    float nr1 = fmaf(c, r1,  s * i0);
    float ni1 = fmaf(c, i1, -s * r0);
    r0 = nr0; i0 = ni0; r1 = nr1; i1 = ni1;
}
DEV void ry_pair(float& r0, float& i0, float& r1, float& i1, float c, float s) {
    float nr0 = fmaf(c, r0, -s * r1);
    float ni0 = fmaf(c, i0, -s * i1);
    float nr1 = fmaf(c, r1,  s * r0);
    float ni1 = fmaf(c, i1,  s * i0);
    r0 = nr0; i0 = ni0; r1 = nr1; i1 = ni1;
}
DEV void rz_amp(float& r, float& i, float c, float ss) {
    float nr = fmaf(c, r, -ss * i);
    float ni = fmaf(c, i,  ss * r);
    r = nr; i = ni;
}

// ---------- gates on flat-index bit B (B = 7 - qubit), r7-verified ----------
template<int B>
DEV void apply_rx(float (&re)[4], float (&im)[4], int lane, bool px, float c, float s) {
    if constexpr (B == 7) {
        rx_pair(re[0], im[0], re[2], im[2], c, s);
        rx_pair(re[1], im[1], re[3], im[3], c, s);
    } else if constexpr (B == 6) {
        rx_pair(re[0], im[0], re[1], im[1], c, s);
        rx_pair(re[2], im[2], re[3], im[3], c, s);
    } else {
#pragma unroll
        for (int k = 0; k < 4; ++k) {
            float pr = lshfl<B>(re[k], px);
            float pi = lshfl<B>(im[k], px);
            re[k] = fmaf(c, re[k],  s * pi);
            im[k] = fmaf(c, im[k], -s * pr);
        }
    }
}
template<int B>
DEV void apply_ry(float (&re)[4], float (&im)[4], int lane, bool px, float c, float s) {
    if constexpr (B == 7) {
        ry_pair(re[0], im[0], re[2], im[2], c, s);
        ry_pair(re[1], im[1], re[3], im[3], c, s);
    } else if constexpr (B == 6) {
        ry_pair(re[0], im[0], re[1], im[1], c, s);
        ry_pair(re[2], im[2], re[3], im[3], c, s);
    } else {
        float ssel = ((lane >> B) & 1) ? s : -s;
#pragma unroll
        for (int k = 0; k < 4; ++k) {
            float pr = lshfl<B>(re[k], px);
            float pi = lshfl<B>(im[k], px);
            re[k] = fmaf(c, re[k], ssel * pr);
            im[k] = fmaf(c, im[k], ssel * pi);
        }
    }
}
template<int B>
DEV void apply_rz(float (&re)[4], float (&im)[4], int lane, float c, float s) {
    if constexpr (B == 7) {
        rz_amp(re[0], im[0], c, -s); rz_amp(re[1], im[1], c, -s);
        rz_amp(re[2], im[2], c,  s); rz_amp(re[3], im[3], c,  s);
    } else if constexpr (B == 6) {
        rz_amp(re[0], im[0], c, -s); rz_amp(re[1], im[1], c,  s);
        rz_amp(re[2], im[2], c, -s); rz_amp(re[3], im[3], c,  s);
    } else {
        float ss = ((lane >> B) & 1) ? s : -s;
#pragma unroll
        for (int k = 0; k < 4; ++k) rz_amp(re[k], im[k], c, ss);
    }
}
template<int BC, int BT>
DEV void apply_cnot(float (&re)[4], float (&im)[4], int lane, bool px) {
    if constexpr (BC == 7 && BT == 6) {
        float tr = re[2], ti = im[2];
        re[2] = re[3]; im[2] = im[3];
        re[3] = tr;    im[3] = ti;
    } else if constexpr (BC == 6) {
        re[1] = lshfl<5>(re[1], px); im[1] = lshfl<5>(im[1], px);
        re[3] = lshfl<5>(re[3], px); im[3] = lshfl<5>(im[3], px);
    } else if constexpr (BC == 5 && BT == 4) {
        bool ctrl = (lane >> 5) & 1;
#pragma unroll
        for (int k = 0; k < 4; ++k) {
            float pr = lshfl<4>(re[k], px);
            float pi = lshfl<4>(im[k], px);
            re[k] = ctrl ? pr : re[k];
            im[k] = ctrl ? pi : im[k];
        }
    } else if constexpr (BC == 4 && BT == 3) {
#pragma unroll
        for (int k = 0; k < 4; ++k) {
            int r = __float_as_int(re[k]), i = __float_as_int(im[k]);
            re[k] = __int_as_float(dpp_masked<0x128, 0xA, 0xF>(r, r));
            im[k] = __int_as_float(dpp_masked<0x128, 0xA, 0xF>(i, i));
        }
    } else if constexpr (BC == 3 && BT == 2) {
#pragma unroll
        for (int k = 0; k < 4; ++k) {
            int r = __float_as_int(re[k]), i = __float_as_int(im[k]);
            int tr = dpp_full<0x1B>(r), ti = dpp_full<0x1B>(i);
            re[k] = __int_as_float(dpp_masked<0x141, 0xF, 0xC>(r, tr));
            im[k] = __int_as_float(dpp_masked<0x141, 0xF, 0xC>(i, ti));
        }
    } else if constexpr (BC == 2 && BT == 1) {
#pragma unroll
        for (int k = 0; k < 4; ++k) {
            int r = __float_as_int(re[k]), i = __float_as_int(im[k]);
            re[k] = __int_as_float(dpp_masked<0x4E, 0xF, 0xA>(r, r));
            im[k] = __int_as_float(dpp_masked<0x4E, 0xF, 0xA>(i, i));
        }
    } else {
#pragma unroll
        for (int k = 0; k < 4; ++k) {
            re[k] = __int_as_float(dpp_full<0xB4>(__float_as_int(re[k])));
            im[k] = __int_as_float(dpp_full<0xB4>(__float_as_int(im[k])));
        }
    }
}

// ---------- fused kernel: U-gen (blocks 0..31) + encode + GEMM + readout ----------
// r17 structure; ONLY change: poll is ACQUIRE (bounded staleness, real re-read)
// with s_sleep(127) (~8k cyc) between polls -> ~64x fewer cache invalidates
// than r16's storm, and no r17-style L1-staleness stall.

__global__ __launch_bounds__(512, 2) void qa_fused(
    const float* __restrict__ x, const float* __restrict__ params,
    f16* __restrict__ Bre, f16* __restrict__ Bim, u32* __restrict__ flag,
    float* __restrict__ out, int batch)
{
    __shared__ float gs[96];
    __shared__ __align__(16) f16 Ar[32 * 256];
    __shared__ __align__(16) f16 Ai[32 * 256];
    __shared__ float zb[4][32][8];

    int tid  = threadIdx.x;
    int w    = tid >> 6, lane = tid & 63;
    int gid  = blockIdx.x;
    bool px  = probe32(lane);

    // ================= producer phase: blocks 0..31, wave w -> basis j =================
    if (gid < 32) {
        if (tid < 48) {
            float th = params[tid] * 0.5f;
            gs[2 * tid]     = __cosf(th);
            gs[2 * tid + 1] = __sinf(th);
        }
        __syncthreads();

        int j = gid * 8 + w;
        float re[4], im[4];
#pragma unroll
        for (int k = 0; k < 4; ++k) {
            re[k] = ((j >> 6) == k && (j & 63) == lane) ? 1.f : 0.f;
            im[k] = 0.f;
        }

#define VQ(l, i) { const int jj = (l) * 24 + (i) * 3;                       \
                   apply_ry<7 - (i)>(re, im, lane, px, gs[2*jj],   gs[2*jj+1]); \
                   apply_rz<7 - (i)>(re, im, lane,     gs[2*jj+2], gs[2*jj+3]); }
#define CN(i)    apply_cnot<7 - (i), 6 - (i)>(re, im, lane, px);
#define RXQ(l,i) { const int jj = (l) * 24 + (i) * 3 + 2;                   \
                   apply_rx<7 - (i)>(re, im, lane, px, gs[2*jj], gs[2*jj+1]); }
#define LAYER(l) \
    VQ(l,0) CN(0) VQ(l,1) CN(1) VQ(l,2) CN(2) VQ(l,3) CN(3) \
    VQ(l,4) CN(4) VQ(l,5) CN(5) VQ(l,6) CN(6) VQ(l,7)       \
    RXQ(l,0) RXQ(l,1) RXQ(l,2) RXQ(l,3) RXQ(l,4) RXQ(l,5) RXQ(l,6) RXQ(l,7)

        LAYER(0)
        LAYER(1)
#undef LAYER
#undef RXQ
#undef CN
#undef VQ

        // coalesced writeout via LDS transpose (reuse Ar/Ai as Lr/Li)
#pragma unroll
        for (int k = 0; k < 4; ++k) {
            int idx = k * 64 + lane;
            Ar[w * 256 + idx] = (f16)re[k];
            Ai[w * 256 + idx] = (f16)im[k];
        }
        __syncthreads();
        {
            int idx  = tid & 255;
            bool isim = tid >= 256;
            const f16* src = isim ? Ai : Ar;
            f16x8 v;
#pragma unroll
            for (int wv = 0; wv < 8; ++wv) v[wv] = src[wv * 256 + idx];
            f16* dst = isim ? Bim : Bre;
            int kb = gid >> 2, joff = (gid & 3) * 8;
            *reinterpret_cast<f16x8*>(&dst[(kb * 256 + idx) * 32 + joff]) = v;
        }
        __threadfence();     // release B stores device-wide
        __syncthreads();     // all waves done (and Ar/Ai reuse complete)
        if (tid == 0) atomicAdd(flag, 1u);
    }

    // ================= encode phase: all blocks, rows b0..b0+31 =================
    int b0 = gid * 32;
    bool active = (b0 < batch);

    if (active) {
        int pcl = __popc((u32)lane);
        const int kpc[4] = { 0, 1, 1, 2 };
#pragma unroll
        for (int e = 0; e < 4; ++e) {
            int rl = w * 4 + e;
            const float* xb = x + (b0 + rl) * 8;
            float4 xlo = *(const float4*)xb;
            float4 xhi = *(const float4*)(xb + 4);
            float c_[8], s_[8];
            __sincosf(xlo.x * 0.5f, &s_[0], &c_[0]);
            __sincosf(xlo.y * 0.5f, &s_[1], &c_[1]);
            __sincosf(xlo.z * 0.5f, &s_[2], &c_[2]);
            __sincosf(xlo.w * 0.5f, &s_[3], &c_[3]);
            __sincosf(xhi.x * 0.5f, &s_[4], &c_[4]);
            __sincosf(xhi.y * 0.5f, &s_[5], &c_[5]);
            __sincosf(xhi.z * 0.5f, &s_[6], &c_[6]);
            __sincosf(xhi.w * 0.5f, &s_[7], &c_[7]);

            float m6;
            m6  = ((lane >> 5) & 1) ? s_[2] : c_[2];
            m6 *= ((lane >> 4) & 1) ? s_[3] : c_[3];
            m6 *= ((lane >> 3) & 1) ? s_[4] : c_[4];
            m6 *= ((lane >> 2) & 1) ? s_[5] : c_[5];
            m6 *= ((lane >> 1) & 1) ? s_[6] : c_[6];
            m6 *= ( lane       & 1) ? s_[7] : c_[7];
            float kf[4] = { c_[0] * c_[1], c_[0] * s_[1], s_[0] * c_[1], s_[0] * s_[1] };
            int sw = (rl & 7) << 3;
#pragma unroll
            for (int k = 0; k < 4; ++k) {
                float mk = m6 * kf[k];
                int p = pcl + kpc[k];
                float sgn = (p & 2) ? -mk : mk;
                float vre = (p & 1) ? 0.f : sgn;
                float vim = (p & 1) ? -sgn : 0.f;
                int j  = k * 64 + lane;
                int hi = rl * 256 + (j ^ sw);
                Ar[hi] = (f16)vre;
                Ai[hi] = (f16)vim;
            }
        }
    }
    __syncthreads();

    // ===== wait for all 32 producer blocks (ACQUIRE poll, slow cadence) =====
    if (tid == 0) {
        while (__hip_atomic_load(flag, __ATOMIC_ACQUIRE, __HIP_MEMORY_SCOPE_AGENT) < 32u)
            __builtin_amdgcn_s_sleep(127);
    }
    __syncthreads();
    __threadfence();         // propagate acquire to all waves of the block

    if (!active) return;

    // ================= K loop: 8 steps of 32, 16 MFMAs each =================
    f32x4 accre[4], accim[4];
#pragma unroll
    for (int t = 0; t < 4; ++t) { accre[t] = (f32x4)0.f; accim[t] = (f32x4)0.f; }

    int rg   = w >> 2, cg = w & 3;
    int colbase = cg * 64 + (lane & 15);
    int arow    = rg * 16 + (lane & 15);
    int kg      = lane >> 4;
    const f16x8* B8re = reinterpret_cast<const f16x8*>(Bre);
    const f16x8* B8im = reinterpret_cast<const f16x8*>(Bim);

#pragma unroll
    for (int kb = 0; kb < 8; ++kb) {
        int afi = arow * 32 + ((kb * 4 + kg) ^ (arow & 7));
        f16x8 are = *reinterpret_cast<const f16x8*>(&Ar[afi * 8]);
        f16x8 aim = *reinterpret_cast<const f16x8*>(&Ai[afi * 8]);
        f16x8 ain;
#pragma unroll
        for (int i = 0; i < 8; ++i) ain[i] = -aim[i];
#pragma unroll
        for (int t = 0; t < 4; ++t) {
            int idx = colbase + t * 16;
            int bo  = (kb * 256 + idx) * 4 + kg;
            f16x8 bre = B8re[bo];
            f16x8 bim = B8im[bo];
            accre[t] = __builtin_amdgcn_mfma_f32_16x16x32_f16(are, bre, accre[t], 0, 0, 0);
            accre[t] = __builtin_amdgcn_mfma_f32_16x16x32_f16(ain, bim, accre[t], 0, 0, 0);
            accim[t] = __builtin_amdgcn_mfma_f32_16x16x32_f16(are, bim, accim[t], 0, 0, 0);
            accim[t] = __builtin_amdgcn_mfma_f32_16x16x32_f16(aim, bre, accim[t], 0, 0, 0);
        }
    }

    // ================= Walsh epilogue =================
    float z[4][8];
#pragma unroll
    for (int r = 0; r < 4; ++r)
#pragma unroll
        for (int q = 0; q < 8; ++q) z[r][q] = 0.f;

#pragma unroll
    for (int t = 0; t < 4; ++t) {
        int idx = colbase + t * 16;
#pragma unroll
        for (int r = 0; r < 4; ++r) {
            float cr = accre[t][r], ci = accim[t][r];
            float p = fmaf(cr, cr, ci * ci);
#pragma unroll
            for (int q = 0; q < 8; ++q)
                z[r][q] += ((idx >> (7 - q)) & 1) ? -p : p;
        }
    }

#pragma unroll
    for (int r = 0; r < 4; ++r)
#pragma unroll
        for (int q = 0; q < 8; ++q) {
            z[r][q] += lshfl<0>(z[r][q], false);
            z[r][q] += lshfl<1>(z[r][q], false);
            z[r][q] += lshfl<2>(z[r][q], false);
            z[r][q] += lshfl<3>(z[r][q], false);
        }

    if ((lane & 15) < 8) {
        int q = lane & 7;
#pragma unroll
        for (int r = 0; r < 4; ++r)
            zb[cg][rg * 16 + (lane >> 4) * 4 + r][q] = z[r][q];
    }
    __syncthreads();

    if (tid < 256) {
        int row = tid >> 3, q = tid & 7;
        float v = zb[0][row][q] + zb[1][row][q] + zb[2][row][q] + zb[3][row][q];
        out[(b0 + row) * 8 + q] = v;
    }
}

extern "C" void kernel_launch(void* const* d_in, const int* in_sizes, int n_in,
                              void* d_out, int out_size, void* d_ws, size_t ws_size,
                              hipStream_t stream) {
    const float* x      = (const float*)d_in[0];   // (BATCH, 8)
    const float* params = (const float*)d_in[1];   // (2, 8, 3) = 48
    float* out = (float*)d_out;

    f16* Bre  = (f16*)d_ws;                        // 128 KB
    f16* Bim  = Bre + 65536;                       // 128 KB
    u32* flag = (u32*)((char*)d_ws + 262144);      // 4 B

    int batch = in_sizes[0] / 8;

    hipMemsetAsync(flag, 0, 4, stream);

    int blocks = (batch + 31) / 32;
    if (blocks < 32) blocks = 32;                  // producers must exist
    qa_fused<<<blocks, 512, 0, stream>>>(x, params, Bre, Bim, flag, out, batch);
}

// Round 19
// 51.142 us; speedup vs baseline: 1.3726x; 1.3726x over previous
//
#include <hip/hip_runtime.h>
#include <hip/hip_cooperative_groups.h>

namespace cg = cooperative_groups;

#define DEV __device__ __forceinline__

typedef unsigned u32;
typedef u32 u32x2 __attribute__((ext_vector_type(2)));
typedef _Float16 f16;
typedef f16   f16x8 __attribute__((ext_vector_type(8)));
typedef float f32x4 __attribute__((ext_vector_type(4)));

// ---------- DPP helpers ----------
template<int CTRL>
DEV int dpp_full(int src) {
    return __builtin_amdgcn_update_dpp(src, src, CTRL, 0xF, 0xF, false);
}
template<int CTRL, int RM, int BM>
DEV int dpp_masked(int old, int src) {
    return __builtin_amdgcn_update_dpp(old, src, CTRL, RM, BM, false);
}

// ---------- cross-lane xor-shuffle (r7-proven mix) ----------
template<int B>
DEV float lshfl(float x, bool px) {
    int xi = __float_as_int(x);
    if constexpr (B == 0) {
        return __int_as_float(dpp_full<0xB1>(xi));          // xor1
    } else if constexpr (B == 1) {
        return __int_as_float(dpp_full<0x4E>(xi));          // xor2
    } else if constexpr (B == 2) {
        return __int_as_float(__builtin_amdgcn_ds_swizzle(xi, 0x101F)); // xor4
    } else if constexpr (B == 3) {
        return __int_as_float(dpp_full<0x128>(xi));         // xor8
    } else if constexpr (B == 4) {
        return __int_as_float(__builtin_amdgcn_ds_swizzle(xi, 0x401F)); // xor16
    } else {
        u32x2 r = __builtin_amdgcn_permlane32_swap((u32)xi, (u32)xi, false, false);
        return __int_as_float((int)(px ? r.x : r.y));
    }
}

DEV bool probe32(int lane) {
    u32 p = (u32)((lane >> 5) & 1);
    u32x2 r = __builtin_amdgcn_permlane32_swap(p, p, false, false);
    return r.x == (p ^ 1u);
}

// ---------- complex pair primitives (fp32) ----------
DEV void rx_pair(float& r0, float& i0, float& r1, float& i1, float c, float s) {
    float nr0 = fmaf(c, r0,  s * i1);
    float ni0 = fmaf(c, i0, -s * r1);
    float nr1 = fmaf(c, r1,  s * i0);
    float ni1 = fmaf(c, i1, -s * r0);
    r0 = nr0; i0 = ni0; r1 = nr1; i1 = ni1;
}
DEV void ry_pair(float& r0, float& i0, float& r1, float& i1, float c, float s) {
    float nr0 = fmaf(c, r0, -s * r1);
    float ni0 = fmaf(c, i0, -s * i1);
    float nr1 = fmaf(c, r1,  s * r0);
    float ni1 = fmaf(c, i1,  s * i0);
    r0 = nr0; i0 = ni0; r1 = nr1; i1 = ni1;
}
DEV void rz_amp(float& r, float& i, float c, float ss) {
    float nr = fmaf(c, r, -ss * i);
    float ni = fmaf(c, i,  ss * r);
    r = nr; i = ni;
}

// ---------- gates on flat-index bit B (B = 7 - qubit), r7-verified ----------
template<int B>
DEV void apply_rx(float (&re)[4], float (&im)[4], int lane, bool px, float c, float s) {
    if constexpr (B == 7) {
        rx_pair(re[0], im[0], re[2], im[2], c, s);
        rx_pair(re[1], im[1], re[3], im[3], c, s);
    } else if constexpr (B == 6) {
        rx_pair(re[0], im[0], re[1], im[1], c, s);
        rx_pair(re[2], im[2], re[3], im[3], c, s);
    } else {
#pragma unroll
        for (int k = 0; k < 4; ++k) {
            float pr = lshfl<B>(re[k], px);
            float pi = lshfl<B>(im[k], px);
            re[k] = fmaf(c, re[k],  s * pi);
            im[k] = fmaf(c, im[k], -s * pr);
        }
    }
}
template<int B>
DEV void apply_ry(float (&re)[4], float (&im)[4], int lane, bool px, float c, float s) {
    if constexpr (B == 7) {
        ry_pair(re[0], im[0], re[2], im[2], c, s);
        ry_pair(re[1], im[1], re[3], im[3], c, s);
    } else if constexpr (B == 6) {
        ry_pair(re[0], im[0], re[1], im[1], c, s);
        ry_pair(re[2], im[2], re[3], im[3], c, s);
    } else {
        float ssel = ((lane >> B) & 1) ? s : -s;
#pragma unroll
        for (int k = 0; k < 4; ++k) {
            float pr = lshfl<B>(re[k], px);
            float pi = lshfl<B>(im[k], px);
            re[k] = fmaf(c, re[k], ssel * pr);
            im[k] = fmaf(c, im[k], ssel * pi);
        }
    }
}
template<int B>
DEV void apply_rz(float (&re)[4], float (&im)[4], int lane, float c, float s) {
    if constexpr (B == 7) {
        rz_amp(re[0], im[0], c, -s); rz_amp(re[1], im[1], c, -s);
        rz_amp(re[2], im[2], c,  s); rz_amp(re[3], im[3], c,  s);
    } else if constexpr (B == 6) {
        rz_amp(re[0], im[0], c, -s); rz_amp(re[1], im[1], c,  s);
        rz_amp(re[2], im[2], c, -s); rz_amp(re[3], im[3], c,  s);
    } else {
        float ss = ((lane >> B) & 1) ? s : -s;
#pragma unroll
        for (int k = 0; k < 4; ++k) rz_amp(re[k], im[k], c, ss);
    }
}
template<int BC, int BT>
DEV void apply_cnot(float (&re)[4], float (&im)[4], int lane, bool px) {
    if constexpr (BC == 7 && BT == 6) {
        float tr = re[2], ti = im[2];
        re[2] = re[3]; im[2] = im[3];
        re[3] = tr;    im[3] = ti;
    } else if constexpr (BC == 6) {
        re[1] = lshfl<5>(re[1], px); im[1] = lshfl<5>(im[1], px);
        re[3] = lshfl<5>(re[3], px); im[3] = lshfl<5>(im[3], px);
    } else if constexpr (BC == 5 && BT == 4) {
        bool ctrl = (lane >> 5) & 1;
#pragma unroll
        for (int k = 0; k < 4; ++k) {
            float pr = lshfl<4>(re[k], px);
            float pi = lshfl<4>(im[k], px);
            re[k] = ctrl ? pr : re[k];
            im[k] = ctrl ? pi : im[k];
        }
    } else if constexpr (BC == 4 && BT == 3) {
#pragma unroll
        for (int k = 0; k < 4; ++k) {
            int r = __float_as_int(re[k]), i = __float_as_int(im[k]);
            re[k] = __int_as_float(dpp_masked<0x128, 0xA, 0xF>(r, r));
            im[k] = __int_as_float(dpp_masked<0x128, 0xA, 0xF>(i, i));
        }
    } else if constexpr (BC == 3 && BT == 2) {
#pragma unroll
        for (int k = 0; k < 4; ++k) {
            int r = __float_as_int(re[k]), i = __float_as_int(im[k]);
            int tr = dpp_full<0x1B>(r), ti = dpp_full<0x1B>(i);
            re[k] = __int_as_float(dpp_masked<0x141, 0xF, 0xC>(r, tr));
            im[k] = __int_as_float(dpp_masked<0x141, 0xF, 0xC>(i, ti));
        }
    } else if constexpr (BC == 2 && BT == 1) {
#pragma unroll
        for (int k = 0; k < 4; ++k) {
            int r = __float_as_int(re[k]), i = __float_as_int(im[k]);
            re[k] = __int_as_float(dpp_masked<0x4E, 0xF, 0xA>(r, r));
            im[k] = __int_as_float(dpp_masked<0x4E, 0xF, 0xA>(i, i));
        }
    } else {
#pragma unroll
        for (int k = 0; k < 4; ++k) {
            re[k] = __int_as_float(dpp_full<0xB4>(__float_as_int(re[k])));
            im[k] = __int_as_float(dpp_full<0xB4>(__float_as_int(im[k])));
        }
    }
}

// ---------- fused kernel: U-gen (blocks 0..31) + encode + grid.sync + GEMM ----------
// Same body as r18; sync is the cooperative grid barrier (runtime/HW-backed),
// no hand-rolled flag, no memset node.

__global__ __launch_bounds__(512, 2) void qa_fused(
    const float* __restrict__ x, const float* __restrict__ params,
    f16* __restrict__ Bre, f16* __restrict__ Bim,
    float* __restrict__ out, int batch)
{
    __shared__ float gs[96];
    __shared__ __align__(16) f16 Ar[32 * 256];
    __shared__ __align__(16) f16 Ai[32 * 256];
    __shared__ float zb[4][32][8];

    int tid  = threadIdx.x;
    int w    = tid >> 6, lane = tid & 63;
    int gid  = blockIdx.x;
    bool px  = probe32(lane);

    // ================= producer phase: blocks 0..31, wave w -> basis j =================
    if (gid < 32) {
        if (tid < 48) {
            float th = params[tid] * 0.5f;
            gs[2 * tid]     = __cosf(th);
            gs[2 * tid + 1] = __sinf(th);
        }
        __syncthreads();

        int j = gid * 8 + w;
        float re[4], im[4];
#pragma unroll
        for (int k = 0; k < 4; ++k) {
            re[k] = ((j >> 6) == k && (j & 63) == lane) ? 1.f : 0.f;
            im[k] = 0.f;
        }

#define VQ(l, i) { const int jj = (l) * 24 + (i) * 3;                       \
                   apply_ry<7 - (i)>(re, im, lane, px, gs[2*jj],   gs[2*jj+1]); \
                   apply_rz<7 - (i)>(re, im, lane,     gs[2*jj+2], gs[2*jj+3]); }
#define CN(i)    apply_cnot<7 - (i), 6 - (i)>(re, im, lane, px);
#define RXQ(l,i) { const int jj = (l) * 24 + (i) * 3 + 2;                   \
                   apply_rx<7 - (i)>(re, im, lane, px, gs[2*jj], gs[2*jj+1]); }
#define LAYER(l) \
    VQ(l,0) CN(0) VQ(l,1) CN(1) VQ(l,2) CN(2) VQ(l,3) CN(3) \
    VQ(l,4) CN(4) VQ(l,5) CN(5) VQ(l,6) CN(6) VQ(l,7)       \
    RXQ(l,0) RXQ(l,1) RXQ(l,2) RXQ(l,3) RXQ(l,4) RXQ(l,5) RXQ(l,6) RXQ(l,7)

        LAYER(0)
        LAYER(1)
#undef LAYER
#undef RXQ
#undef CN
#undef VQ

        // coalesced writeout via LDS transpose (reuse Ar/Ai as Lr/Li)
#pragma unroll
        for (int k = 0; k < 4; ++k) {
            int idx = k * 64 + lane;
            Ar[w * 256 + idx] = (f16)re[k];
            Ai[w * 256 + idx] = (f16)im[k];
        }
        __syncthreads();
        {
            int idx  = tid & 255;
            bool isim = tid >= 256;
            const f16* src = isim ? Ai : Ar;
            f16x8 v;
#pragma unroll
            for (int wv = 0; wv < 8; ++wv) v[wv] = src[wv * 256 + idx];
            f16* dst = isim ? Bim : Bre;
            int kb = gid >> 2, joff = (gid & 3) * 8;
            *reinterpret_cast<f16x8*>(&dst[(kb * 256 + idx) * 32 + joff]) = v;
        }
        __syncthreads();     // Ar/Ai reuse complete before encode overwrites
    }

    // ================= encode phase: all blocks, rows b0..b0+31 =================
    int b0 = gid * 32;
    bool active = (b0 < batch);

    if (active) {
        int pcl = __popc((u32)lane);
        const int kpc[4] = { 0, 1, 1, 2 };
#pragma unroll
        for (int e = 0; e < 4; ++e) {
            int rl = w * 4 + e;
            const float* xb = x + (b0 + rl) * 8;
            float4 xlo = *(const float4*)xb;
            float4 xhi = *(const float4*)(xb + 4);
            float c_[8], s_[8];
            __sincosf(xlo.x * 0.5f, &s_[0], &c_[0]);
            __sincosf(xlo.y * 0.5f, &s_[1], &c_[1]);
            __sincosf(xlo.z * 0.5f, &s_[2], &c_[2]);
            __sincosf(xlo.w * 0.5f, &s_[3], &c_[3]);
            __sincosf(xhi.x * 0.5f, &s_[4], &c_[4]);
            __sincosf(xhi.y * 0.5f, &s_[5], &c_[5]);
            __sincosf(xhi.z * 0.5f, &s_[6], &c_[6]);
            __sincosf(xhi.w * 0.5f, &s_[7], &c_[7]);

            float m6;
            m6  = ((lane >> 5) & 1) ? s_[2] : c_[2];
            m6 *= ((lane >> 4) & 1) ? s_[3] : c_[3];
            m6 *= ((lane >> 3) & 1) ? s_[4] : c_[4];
            m6 *= ((lane >> 2) & 1) ? s_[5] : c_[5];
            m6 *= ((lane >> 1) & 1) ? s_[6] : c_[6];
            m6 *= ( lane       & 1) ? s_[7] : c_[7];
            float kf[4] = { c_[0] * c_[1], c_[0] * s_[1], s_[0] * c_[1], s_[0] * s_[1] };
            int sw = (rl & 7) << 3;
#pragma unroll
            for (int k = 0; k < 4; ++k) {
                float mk = m6 * kf[k];
                int p = pcl + kpc[k];
                float sgn = (p & 2) ? -mk : mk;
                float vre = (p & 1) ? 0.f : sgn;
                float vim = (p & 1) ? -sgn : 0.f;
                int j  = k * 64 + lane;
                int hi = rl * 256 + (j ^ sw);
                Ar[hi] = (f16)vre;
                Ai[hi] = (f16)vim;
            }
        }
    }

    // ================= grid-wide barrier (cooperative, HW/runtime-backed) =================
    cg::this_grid().sync();

    if (!active) return;

    // ================= K loop: 8 steps of 32, 16 MFMAs each =================
    f32x4 accre[4], accim[4];
#pragma unroll
    for (int t = 0; t < 4; ++t) { accre[t] = (f32x4)0.f; accim[t] = (f32x4)0.f; }

    int rg   = w >> 2, cg_ = w & 3;
    int colbase = cg_ * 64 + (lane & 15);
    int arow    = rg * 16 + (lane & 15);
    int kg      = lane >> 4;
    const f16x8* B8re = reinterpret_cast<const f16x8*>(Bre);
    const f16x8* B8im = reinterpret_cast<const f16x8*>(Bim);

#pragma unroll
    for (int kb = 0; kb < 8; ++kb) {
        int afi = arow * 32 + ((kb * 4 + kg) ^ (arow & 7));
        f16x8 are = *reinterpret_cast<const f16x8*>(&Ar[afi * 8]);
        f16x8 aim = *reinterpret_cast<const f16x8*>(&Ai[afi * 8]);
        f16x8 ain;
#pragma unroll
        for (int i = 0; i < 8; ++i) ain[i] = -aim[i];
#pragma unroll
        for (int t = 0; t < 4; ++t) {
            int idx = colbase + t * 16;
            int bo  = (kb * 256 + idx) * 4 + kg;
            f16x8 bre = B8re[bo];
            f16x8 bim = B8im[bo];
            accre[t] = __builtin_amdgcn_mfma_f32_16x16x32_f16(are, bre, accre[t], 0, 0, 0);
            accre[t] = __builtin_amdgcn_mfma_f32_16x16x32_f16(ain, bim, accre[t], 0, 0, 0);
            accim[t] = __builtin_amdgcn_mfma_f32_16x16x32_f16(are, bim, accim[t], 0, 0, 0);
            accim[t] = __builtin_amdgcn_mfma_f32_16x16x32_f16(aim, bre, accim[t], 0, 0, 0);
        }
    }

    // ================= Walsh epilogue =================
    float z[4][8];
#pragma unroll
    for (int r = 0; r < 4; ++r)
#pragma unroll
        for (int q = 0; q < 8; ++q) z[r][q] = 0.f;

#pragma unroll
    for (int t = 0; t < 4; ++t) {
        int idx = colbase + t * 16;
#pragma unroll
        for (int r = 0; r < 4; ++r) {
            float cr = accre[t][r], ci = accim[t][r];
            float p = fmaf(cr, cr, ci * ci);
#pragma unroll
            for (int q = 0; q < 8; ++q)
                z[r][q] += ((idx >> (7 - q)) & 1) ? -p : p;
        }
    }

#pragma unroll
    for (int r = 0; r < 4; ++r)
#pragma unroll
        for (int q = 0; q < 8; ++q) {
            z[r][q] += lshfl<0>(z[r][q], false);
            z[r][q] += lshfl<1>(z[r][q], false);
            z[r][q] += lshfl<2>(z[r][q], false);
            z[r][q] += lshfl<3>(z[r][q], false);
        }

    if ((lane & 15) < 8) {
        int q = lane & 7;
#pragma unroll
        for (int r = 0; r < 4; ++r)
            zb[cg_][rg * 16 + (lane >> 4) * 4 + r][q] = z[r][q];
    }
    __syncthreads();

    if (tid < 256) {
        int row = tid >> 3, q = tid & 7;
        float v = zb[0][row][q] + zb[1][row][q] + zb[2][row][q] + zb[3][row][q];
        out[(b0 + row) * 8 + q] = v;
    }
}

extern "C" void kernel_launch(void* const* d_in, const int* in_sizes, int n_in,
                              void* d_out, int out_size, void* d_ws, size_t ws_size,
                              hipStream_t stream) {
    const float* x      = (const float*)d_in[0];   // (BATCH, 8)
    const float* params = (const float*)d_in[1];   // (2, 8, 3) = 48
    float* out = (float*)d_out;

    f16* Bre  = (f16*)d_ws;                        // 128 KB
    f16* Bim  = Bre + 65536;                       // 128 KB

    int batch = in_sizes[0] / 8;

    int blocks = (batch + 31) / 32;
    if (blocks < 32) blocks = 32;                  // producers must exist

    void* args[] = { (void*)&x, (void*)&params, (void*)&Bre, (void*)&Bim,
                     (void*)&out, (void*)&batch };
    hipLaunchCooperativeKernel((void*)qa_fused, dim3(blocks), dim3(512),
                               args, 0, stream);
}

// Round 20
// 51.046 us; speedup vs baseline: 1.3752x; 1.0019x over previous
//
#include <hip/hip_runtime.h>
#include <hip/hip_cooperative_groups.h>

namespace cg = cooperative_groups;

#define DEV __device__ __forceinline__

typedef unsigned u32;
typedef u32 u32x2 __attribute__((ext_vector_type(2)));
typedef _Float16 f16;
typedef f16   f16x8 __attribute__((ext_vector_type(8)));
typedef float f32x4 __attribute__((ext_vector_type(4)));

// ---------- DPP helpers ----------
template<int CTRL>
DEV int dpp_full(int src) {
    return __builtin_amdgcn_update_dpp(src, src, CTRL, 0xF, 0xF, false);
}
template<int CTRL, int RM, int BM>
DEV int dpp_masked(int old, int src) {
    return __builtin_amdgcn_update_dpp(old, src, CTRL, RM, BM, false);
}

// ---------- cross-lane xor-shuffle (r7-proven mix) ----------
template<int B>
DEV float lshfl(float x, bool px) {
    int xi = __float_as_int(x);
    if constexpr (B == 0) {
        return __int_as_float(dpp_full<0xB1>(xi));          // xor1
    } else if constexpr (B == 1) {
        return __int_as_float(dpp_full<0x4E>(xi));          // xor2
    } else if constexpr (B == 2) {
        return __int_as_float(__builtin_amdgcn_ds_swizzle(xi, 0x101F)); // xor4
    } else if constexpr (B == 3) {
        return __int_as_float(dpp_full<0x128>(xi));         // xor8
    } else if constexpr (B == 4) {
        return __int_as_float(__builtin_amdgcn_ds_swizzle(xi, 0x401F)); // xor16
    } else {
        u32x2 r = __builtin_amdgcn_permlane32_swap((u32)xi, (u32)xi, false, false);
        return __int_as_float((int)(px ? r.x : r.y));
    }
}

DEV bool probe32(int lane) {
    u32 p = (u32)((lane >> 5) & 1);
    u32x2 r = __builtin_amdgcn_permlane32_swap(p, p, false, false);
    return r.x == (p ^ 1u);
}

// ---------- complex pair primitives (fp32) ----------
DEV void rx_pair(float& r0, float& i0, float& r1, float& i1, float c, float s) {
    float nr0 = fmaf(c, r0,  s * i1);
    float ni0 = fmaf(c, i0, -s * r1);
    float nr1 = fmaf(c, r1,  s * i0);
    float ni1 = fmaf(c, i1, -s * r0);
    r0 = nr0; i0 = ni0; r1 = nr1; i1 = ni1;
}
DEV void ry_pair(float& r0, float& i0, float& r1, float& i1, float c, float s) {
    float nr0 = fmaf(c, r0, -s * r1);
    float ni0 = fmaf(c, i0, -s * i1);
    float nr1 = fmaf(c, r1,  s * r0);
    float ni1 = fmaf(c, i1,  s * i0);
    r0 = nr0; i0 = ni0; r1 = nr1; i1 = ni1;
}
DEV void rz_amp(float& r, float& i, float c, float ss) {
    float nr = fmaf(c, r, -ss * i);
    float ni = fmaf(c, i,  ss * r);
    r = nr; i = ni;
}

// ---------- gates on flat-index bit B (B = 7 - qubit), r7-verified ----------
template<int B>
DEV void apply_rx(float (&re)[4], float (&im)[4], int lane, bool px, float c, float s) {
    if constexpr (B == 7) {
        rx_pair(re[0], im[0], re[2], im[2], c, s);
        rx_pair(re[1], im[1], re[3], im[3], c, s);
    } else if constexpr (B == 6) {
        rx_pair(re[0], im[0], re[1], im[1], c, s);
        rx_pair(re[2], im[2], re[3], im[3], c, s);
    } else {
#pragma unroll
        for (int k = 0; k < 4; ++k) {
            float pr = lshfl<B>(re[k], px);
            float pi = lshfl<B>(im[k], px);
            re[k] = fmaf(c, re[k],  s * pi);
            im[k] = fmaf(c, im[k], -s * pr);
        }
    }
}
template<int B>
DEV void apply_ry(float (&re)[4], float (&im)[4], int lane, bool px, float c, float s) {
    if constexpr (B == 7) {
        ry_pair(re[0], im[0], re[2], im[2], c, s);
        ry_pair(re[1], im[1], re[3], im[3], c, s);
    } else if constexpr (B == 6) {
        ry_pair(re[0], im[0], re[1], im[1], c, s);
        ry_pair(re[2], im[2], re[3], im[3], c, s);
    } else {
        float ssel = ((lane >> B) & 1) ? s : -s;
#pragma unroll
        for (int k = 0; k < 4; ++k) {
            float pr = lshfl<B>(re[k], px);
            float pi = lshfl<B>(im[k], px);
            re[k] = fmaf(c, re[k], ssel * pr);
            im[k] = fmaf(c, im[k], ssel * pi);
        }
    }
}
template<int B>
DEV void apply_rz(float (&re)[4], float (&im)[4], int lane, float c, float s) {
    if constexpr (B == 7) {
        rz_amp(re[0], im[0], c, -s); rz_amp(re[1], im[1], c, -s);
        rz_amp(re[2], im[2], c,  s); rz_amp(re[3], im[3], c,  s);
    } else if constexpr (B == 6) {
        rz_amp(re[0], im[0], c, -s); rz_amp(re[1], im[1], c,  s);
        rz_amp(re[2], im[2], c, -s); rz_amp(re[3], im[3], c,  s);
    } else {
        float ss = ((lane >> B) & 1) ? s : -s;
#pragma unroll
        for (int k = 0; k < 4; ++k) rz_amp(re[k], im[k], c, ss);
    }
}
template<int BC, int BT>
DEV void apply_cnot(float (&re)[4], float (&im)[4], int lane, bool px) {
    if constexpr (BC == 7 && BT == 6) {
        float tr = re[2], ti = im[2];
        re[2] = re[3]; im[2] = im[3];
        re[3] = tr;    im[3] = ti;
    } else if constexpr (BC == 6) {
        re[1] = lshfl<5>(re[1], px); im[1] = lshfl<5>(im[1], px);
        re[3] = lshfl<5>(re[3], px); im[3] = lshfl<5>(im[3], px);
    } else if constexpr (BC == 5 && BT == 4) {
        bool ctrl = (lane >> 5) & 1;
#pragma unroll
        for (int k = 0; k < 4; ++k) {
            float pr = lshfl<4>(re[k], px);
            float pi = lshfl<4>(im[k], px);
            re[k] = ctrl ? pr : re[k];
            im[k] = ctrl ? pi : im[k];
        }
    } else if constexpr (BC == 4 && BT == 3) {
#pragma unroll
        for (int k = 0; k < 4; ++k) {
            int r = __float_as_int(re[k]), i = __float_as_int(im[k]);
            re[k] = __int_as_float(dpp_masked<0x128, 0xA, 0xF>(r, r));
            im[k] = __int_as_float(dpp_masked<0x128, 0xA, 0xF>(i, i));
        }
    } else if constexpr (BC == 3 && BT == 2) {
#pragma unroll
        for (int k = 0; k < 4; ++k) {
            int r = __float_as_int(re[k]), i = __float_as_int(im[k]);
            int tr = dpp_full<0x1B>(r), ti = dpp_full<0x1B>(i);
            re[k] = __int_as_float(dpp_masked<0x141, 0xF, 0xC>(r, tr));
            im[k] = __int_as_float(dpp_masked<0x141, 0xF, 0xC>(i, ti));
        }
    } else if constexpr (BC == 2 && BT == 1) {
#pragma unroll
        for (int k = 0; k < 4; ++k) {
            int r = __float_as_int(re[k]), i = __float_as_int(im[k]);
            re[k] = __int_as_float(dpp_masked<0x4E, 0xF, 0xA>(r, r));
            im[k] = __int_as_float(dpp_masked<0x4E, 0xF, 0xA>(i, i));
        }
    } else {
#pragma unroll
        for (int k = 0; k < 4; ++k) {
            re[k] = __int_as_float(dpp_full<0xB4>(__float_as_int(re[k])));
            im[k] = __int_as_float(dpp_full<0xB4>(__float_as_int(im[k])));
        }
    }
}

// ---------- fused kernel: U-gen (blocks 0..31) + encode + grid.sync + GEMM ----------
// Same body as r18; sync is the cooperative grid barrier (runtime/HW-backed),
// no hand-rolled flag, no memset node.

__global__ __launch_bounds__(512, 2) void qa_fused(
    const float* __restrict__ x, const float* __restrict__ params,
    f16* __restrict__ Bre, f16* __restrict__ Bim,
    float* __restrict__ out, int batch)
{
    __shared__ float gs[96];
    __shared__ __align__(16) f16 Ar[32 * 256];
    __shared__ __align__(16) f16 Ai[32 * 256];
    __shared__ float zb[4][32][8];

    int tid  = threadIdx.x;
    int w    = tid >> 6, lane = tid & 63;
    int gid  = blockIdx.x;
    bool px  = probe32(lane);

    // ================= producer phase: blocks 0..31, wave w -> basis j =================
    if (gid < 32) {
        if (tid < 48) {
            float th = params[tid] * 0.5f;
            gs[2 * tid]     = __cosf(th);
            gs[2 * tid + 1] = __sinf(th);
        }
        __syncthreads();

        int j = gid * 8 + w;
        float re[4], im[4];
#pragma unroll
        for (int k = 0; k < 4; ++k) {
            re[k] = ((j >> 6) == k && (j & 63) == lane) ? 1.f : 0.f;
            im[k] = 0.f;
        }

#define VQ(l, i) { const int jj = (l) * 24 + (i) * 3;                       \
                   apply_ry<7 - (i)>(re, im, lane, px, gs[2*jj],   gs[2*jj+1]); \
                   apply_rz<7 - (i)>(re, im, lane,     gs[2*jj+2], gs[2*jj+3]); }
#define CN(i)    apply_cnot<7 - (i), 6 - (i)>(re, im, lane, px);
#define RXQ(l,i) { const int jj = (l) * 24 + (i) * 3 + 2;                   \
                   apply_rx<7 - (i)>(re, im, lane, px, gs[2*jj], gs[2*jj+1]); }
#define LAYER(l) \
    VQ(l,0) CN(0) VQ(l,1) CN(1) VQ(l,2) CN(2) VQ(l,3) CN(3) \
    VQ(l,4) CN(4) VQ(l,5) CN(5) VQ(l,6) CN(6) VQ(l,7)       \
    RXQ(l,0) RXQ(l,1) RXQ(l,2) RXQ(l,3) RXQ(l,4) RXQ(l,5) RXQ(l,6) RXQ(l,7)

        LAYER(0)
        LAYER(1)
#undef LAYER
#undef RXQ
#undef CN
#undef VQ

        // coalesced writeout via LDS transpose (reuse Ar/Ai as Lr/Li)
#pragma unroll
        for (int k = 0; k < 4; ++k) {
            int idx = k * 64 + lane;
            Ar[w * 256 + idx] = (f16)re[k];
            Ai[w * 256 + idx] = (f16)im[k];
        }
        __syncthreads();
        {
            int idx  = tid & 255;
            bool isim = tid >= 256;
            const f16* src = isim ? Ai : Ar;
            f16x8 v;
#pragma unroll
            for (int wv = 0; wv < 8; ++wv) v[wv] = src[wv * 256 + idx];
            f16* dst = isim ? Bim : Bre;
            int kb = gid >> 2, joff = (gid & 3) * 8;
            *reinterpret_cast<f16x8*>(&dst[(kb * 256 + idx) * 32 + joff]) = v;
        }
        __syncthreads();     // Ar/Ai reuse complete before encode overwrites
    }

    // ================= encode phase: all blocks, rows b0..b0+31 =================
    int b0 = gid * 32;
    bool active = (b0 < batch);

    if (active) {
        int pcl = __popc((u32)lane);
        const int kpc[4] = { 0, 1, 1, 2 };
#pragma unroll
        for (int e = 0; e < 4; ++e) {
            int rl = w * 4 + e;
            const float* xb = x + (b0 + rl) * 8;
            float4 xlo = *(const float4*)xb;
            float4 xhi = *(const float4*)(xb + 4);
            float c_[8], s_[8];
            __sincosf(xlo.x * 0.5f, &s_[0], &c_[0]);
            __sincosf(xlo.y * 0.5f, &s_[1], &c_[1]);
            __sincosf(xlo.z * 0.5f, &s_[2], &c_[2]);
            __sincosf(xlo.w * 0.5f, &s_[3], &c_[3]);
            __sincosf(xhi.x * 0.5f, &s_[4], &c_[4]);
            __sincosf(xhi.y * 0.5f, &s_[5], &c_[5]);
            __sincosf(xhi.z * 0.5f, &s_[6], &c_[6]);
            __sincosf(xhi.w * 0.5f, &s_[7], &c_[7]);

            float m6;
            m6  = ((lane >> 5) & 1) ? s_[2] : c_[2];
            m6 *= ((lane >> 4) & 1) ? s_[3] : c_[3];
            m6 *= ((lane >> 3) & 1) ? s_[4] : c_[4];
            m6 *= ((lane >> 2) & 1) ? s_[5] : c_[5];
            m6 *= ((lane >> 1) & 1) ? s_[6] : c_[6];
            m6 *= ( lane       & 1) ? s_[7] : c_[7];
            float kf[4] = { c_[0] * c_[1], c_[0] * s_[1], s_[0] * c_[1], s_[0] * s_[1] };
            int sw = (rl & 7) << 3;
#pragma unroll
            for (int k = 0; k < 4; ++k) {
                float mk = m6 * kf[k];
                int p = pcl + kpc[k];
                float sgn = (p & 2) ? -mk : mk;
                float vre = (p & 1) ? 0.f : sgn;
                float vim = (p & 1) ? -sgn : 0.f;
                int j  = k * 64 + lane;
                int hi = rl * 256 + (j ^ sw);
                Ar[hi] = (f16)vre;
                Ai[hi] = (f16)vim;
            }
        }
    }

    // ================= grid-wide barrier (cooperative, HW/runtime-backed) =================
    cg::this_grid().sync();

    if (!active) return;

    // ================= K loop: 8 steps of 32, 16 MFMAs each =================
    f32x4 accre[4], accim[4];
#pragma unroll
    for (int t = 0; t < 4; ++t) { accre[t] = (f32x4)0.f; accim[t] = (f32x4)0.f; }

    int rg   = w >> 2, cg_ = w & 3;
    int colbase = cg_ * 64 + (lane & 15);
    int arow    = rg * 16 + (lane & 15);
    int kg      = lane >> 4;
    const f16x8* B8re = reinterpret_cast<const f16x8*>(Bre);
    const f16x8* B8im = reinterpret_cast<const f16x8*>(Bim);

#pragma unroll
    for (int kb = 0; kb < 8; ++kb) {
        int afi = arow * 32 + ((kb * 4 + kg) ^ (arow & 7));
        f16x8 are = *reinterpret_cast<const f16x8*>(&Ar[afi * 8]);
        f16x8 aim = *reinterpret_cast<const f16x8*>(&Ai[afi * 8]);
        f16x8 ain;
#pragma unroll
        for (int i = 0; i < 8; ++i) ain[i] = -aim[i];
#pragma unroll
        for (int t = 0; t < 4; ++t) {
            int idx = colbase + t * 16;
            int bo  = (kb * 256 + idx) * 4 + kg;
            f16x8 bre = B8re[bo];
            f16x8 bim = B8im[bo];
            accre[t] = __builtin_amdgcn_mfma_f32_16x16x32_f16(are, bre, accre[t], 0, 0, 0);
            accre[t] = __builtin_amdgcn_mfma_f32_16x16x32_f16(ain, bim, accre[t], 0, 0, 0);
            accim[t] = __builtin_amdgcn_mfma_f32_16x16x32_f16(are, bim, accim[t], 0, 0, 0);
            accim[t] = __builtin_amdgcn_mfma_f32_16x16x32_f16(aim, bre, accim[t], 0, 0, 0);
        }
    }

    // ================= Walsh epilogue =================
    float z[4][8];
#pragma unroll
    for (int r = 0; r < 4; ++r)
#pragma unroll
        for (int q = 0; q < 8; ++q) z[r][q] = 0.f;

#pragma unroll
    for (int t = 0; t < 4; ++t) {
        int idx = colbase + t * 16;
#pragma unroll
        for (int r = 0; r < 4; ++r) {
            float cr = accre[t][r], ci = accim[t][r];
            float p = fmaf(cr, cr, ci * ci);
#pragma unroll
            for (int q = 0; q < 8; ++q)
                z[r][q] += ((idx >> (7 - q)) & 1) ? -p : p;
        }
    }

#pragma unroll
    for (int r = 0; r < 4; ++r)
#pragma unroll
        for (int q = 0; q < 8; ++q) {
            z[r][q] += lshfl<0>(z[r][q], false);
            z[r][q] += lshfl<1>(z[r][q], false);
            z[r][q] += lshfl<2>(z[r][q], false);
            z[r][q] += lshfl<3>(z[r][q], false);
        }

    if ((lane & 15) < 8) {
        int q = lane & 7;
#pragma unroll
        for (int r = 0; r < 4; ++r)
            zb[cg_][rg * 16 + (lane >> 4) * 4 + r][q] = z[r][q];
    }
    __syncthreads();

    if (tid < 256) {
        int row = tid >> 3, q = tid & 7;
        float v = zb[0][row][q] + zb[1][row][q] + zb[2][row][q] + zb[3][row][q];
        out[(b0 + row) * 8 + q] = v;
    }
}

extern "C" void kernel_launch(void* const* d_in, const int* in_sizes, int n_in,
                              void* d_out, int out_size, void* d_ws, size_t ws_size,
                              hipStream_t stream) {
    const float* x      = (const float*)d_in[0];   // (BATCH, 8)
    const float* params = (const float*)d_in[1];   // (2, 8, 3) = 48
    float* out = (float*)d_out;

    f16* Bre  = (f16*)d_ws;                        // 128 KB
    f16* Bim  = Bre + 65536;                       // 128 KB

    int batch = in_sizes[0] / 8;

    int blocks = (batch + 31) / 32;
    if (blocks < 32) blocks = 32;                  // producers must exist

    void* args[] = { (void*)&x, (void*)&params, (void*)&Bre, (void*)&Bim,
                     (void*)&out, (void*)&batch };
    hipLaunchCooperativeKernel((void*)qa_fused, dim3(blocks), dim3(512),
                               args, 0, stream);
}

// Round 21
// 25.320 us; speedup vs baseline: 2.7725x; 2.0160x over previous
//
#include <hip/hip_runtime.h>

#define DEV __device__ __forceinline__

typedef unsigned u32;
typedef u32 u32x2 __attribute__((ext_vector_type(2)));
typedef _Float16 f16;
typedef f16   f16x8 __attribute__((ext_vector_type(8)));
typedef float f32x4 __attribute__((ext_vector_type(4)));

// ---------- DPP helpers ----------
template<int CTRL>
DEV int dpp_full(int src) {
    return __builtin_amdgcn_update_dpp(src, src, CTRL, 0xF, 0xF, false);
}
template<int CTRL, int RM, int BM>
DEV int dpp_masked(int old, int src) {
    return __builtin_amdgcn_update_dpp(old, src, CTRL, RM, BM, false);
}

// ---------- cross-lane xor-shuffle (r7-proven mix) ----------
template<int B>
DEV float lshfl(float x, bool px) {
    int xi = __float_as_int(x);
    if constexpr (B == 0) {
        return __int_as_float(dpp_full<0xB1>(xi));          // xor1
    } else if constexpr (B == 1) {
        return __int_as_float(dpp_full<0x4E>(xi));          // xor2
    } else if constexpr (B == 2) {
        return __int_as_float(__builtin_amdgcn_ds_swizzle(xi, 0x101F)); // xor4
    } else if constexpr (B == 3) {
        return __int_as_float(dpp_full<0x128>(xi));         // xor8
    } else if constexpr (B == 4) {
        return __int_as_float(__builtin_amdgcn_ds_swizzle(xi, 0x401F)); // xor16
    } else {
        u32x2 r = __builtin_amdgcn_permlane32_swap((u32)xi, (u32)xi, false, false);
        return __int_as_float((int)(px ? r.x : r.y));
    }
}

DEV bool probe32(int lane) {
    u32 p = (u32)((lane >> 5) & 1);
    u32x2 r = __builtin_amdgcn_permlane32_swap(p, p, false, false);
    return r.x == (p ^ 1u);
}

// ---------- complex pair primitives (fp32) ----------
DEV void rx_pair(float& r0, float& i0, float& r1, float& i1, float c, float s) {
    float nr0 = fmaf(c, r0,  s * i1);
    float ni0 = fmaf(c, i0, -s * r1);
    float nr1 = fmaf(c, r1,  s * i0);
    float ni1 = fmaf(c, i1, -s * r0);
    r0 = nr0; i0 = ni0; r1 = nr1; i1 = ni1;
}
DEV void ry_pair(float& r0, float& i0, float& r1, float& i1, float c, float s) {
    float nr0 = fmaf(c, r0, -s * r1);
    float ni0 = fmaf(c, i0, -s * i1);
    float nr1 = fmaf(c, r1,  s * r0);
    float ni1 = fmaf(c, i1,  s * i0);
    r0 = nr0; i0 = ni0; r1 = nr1; i1 = ni1;
}
DEV void rz_amp(float& r, float& i, float c, float ss) {
    float nr = fmaf(c, r, -ss * i);
    float ni = fmaf(c, i,  ss * r);
    r = nr; i = ni;
}

// ---------- gates on flat-index bit B (B = 7 - qubit), r7-verified ----------
template<int B>
DEV void apply_rx(float (&re)[4], float (&im)[4], int lane, bool px, float c, float s) {
    if constexpr (B == 7) {
        rx_pair(re[0], im[0], re[2], im[2], c, s);
        rx_pair(re[1], im[1], re[3], im[3], c, s);
    } else if constexpr (B == 6) {
        rx_pair(re[0], im[0], re[1], im[1], c, s);
        rx_pair(re[2], im[2], re[3], im[3], c, s);
    } else {
#pragma unroll
        for (int k = 0; k < 4; ++k) {
            float pr = lshfl<B>(re[k], px);
            float pi = lshfl<B>(im[k], px);
            re[k] = fmaf(c, re[k],  s * pi);
            im[k] = fmaf(c, im[k], -s * pr);
        }
    }
}
template<int B>
DEV void apply_ry(float (&re)[4], float (&im)[4], int lane, bool px, float c, float s) {
    if constexpr (B == 7) {
        ry_pair(re[0], im[0], re[2], im[2], c, s);
        ry_pair(re[1], im[1], re[3], im[3], c, s);
    } else if constexpr (B == 6) {
        ry_pair(re[0], im[0], re[1], im[1], c, s);
        ry_pair(re[2], im[2], re[3], im[3], c, s);
    } else {
        float ssel = ((lane >> B) & 1) ? s : -s;
#pragma unroll
        for (int k = 0; k < 4; ++k) {
            float pr = lshfl<B>(re[k], px);
            float pi = lshfl<B>(im[k], px);
            re[k] = fmaf(c, re[k], ssel * pr);
            im[k] = fmaf(c, im[k], ssel * pi);
        }
    }
}
template<int B>
DEV void apply_rz(float (&re)[4], float (&im)[4], int lane, float c, float s) {
    if constexpr (B == 7) {
        rz_amp(re[0], im[0], c, -s); rz_amp(re[1], im[1], c, -s);
        rz_amp(re[2], im[2], c,  s); rz_amp(re[3], im[3], c,  s);
    } else if constexpr (B == 6) {
        rz_amp(re[0], im[0], c, -s); rz_amp(re[1], im[1], c,  s);
        rz_amp(re[2], im[2], c, -s); rz_amp(re[3], im[3], c,  s);
    } else {
        float ss = ((lane >> B) & 1) ? s : -s;
#pragma unroll
        for (int k = 0; k < 4; ++k) rz_amp(re[k], im[k], c, ss);
    }
}
template<int BC, int BT>
DEV void apply_cnot(float (&re)[4], float (&im)[4], int lane, bool px) {
    if constexpr (BC == 7 && BT == 6) {
        float tr = re[2], ti = im[2];
        re[2] = re[3]; im[2] = im[3];
        re[3] = tr;    im[3] = ti;
    } else if constexpr (BC == 6) {
        re[1] = lshfl<5>(re[1], px); im[1] = lshfl<5>(im[1], px);
        re[3] = lshfl<5>(re[3], px); im[3] = lshfl<5>(im[3], px);
    } else if constexpr (BC == 5 && BT == 4) {
        bool ctrl = (lane >> 5) & 1;
#pragma unroll
        for (int k = 0; k < 4; ++k) {
            float pr = lshfl<4>(re[k], px);
            float pi = lshfl<4>(im[k], px);
            re[k] = ctrl ? pr : re[k];
            im[k] = ctrl ? pi : im[k];
        }
    } else if constexpr (BC == 4 && BT == 3) {
#pragma unroll
        for (int k = 0; k < 4; ++k) {
            int r = __float_as_int(re[k]), i = __float_as_int(im[k]);
            re[k] = __int_as_float(dpp_masked<0x128, 0xA, 0xF>(r, r));
            im[k] = __int_as_float(dpp_masked<0x128, 0xA, 0xF>(i, i));
        }
    } else if constexpr (BC == 3 && BT == 2) {
#pragma unroll
        for (int k = 0; k < 4; ++k) {
            int r = __float_as_int(re[k]), i = __float_as_int(im[k]);
            int tr = dpp_full<0x1B>(r), ti = dpp_full<0x1B>(i);
            re[k] = __int_as_float(dpp_masked<0x141, 0xF, 0xC>(r, tr));
            im[k] = __int_as_float(dpp_masked<0x141, 0xF, 0xC>(i, ti));
        }
    } else if constexpr (BC == 2 && BT == 1) {
#pragma unroll
        for (int k = 0; k < 4; ++k) {
            int r = __float_as_int(re[k]), i = __float_as_int(im[k]);
            re[k] = __int_as_float(dpp_masked<0x4E, 0xF, 0xA>(r, r));
            im[k] = __int_as_float(dpp_masked<0x4E, 0xF, 0xA>(i, i));
        }
    } else {
#pragma unroll
        for (int k = 0; k < 4; ++k) {
            re[k] = __int_as_float(dpp_full<0xB4>(__float_as_int(re[k])));
            im[k] = __int_as_float(dpp_full<0xB4>(__float_as_int(im[k])));
        }
    }
}

// ---------- kernel 1: build G,H (phase-folded U) as packed MFMA B-operands ----------
// Wave j simulates circuit(e_j); sel = popcount(j)&3 (wave-uniform) folds the
// encoding phase (-i)^pc(j) into the matrix:
//   G[idx,j] = {Ur, Ui, -Ur, -Ui}[sel],  H[idx,j] = {Ui, -Ur, -Ui, Ur}[sel]
// so  Re(Us) = P.G^T, Im(Us) = P.H^T  with P real.  Packing granule
// identical to r14-verified: half_index = (kb*256+idx)*32 + (j&31), kb=j>>5.

__global__ __launch_bounds__(512) void qa_genU(
    const float* __restrict__ params, f16* __restrict__ Bg, f16* __restrict__ Bh)
{
    __shared__ float gs[96];
    __shared__ f16 Lg[8][256];
    __shared__ f16 Lh[8][256];

    int tid  = threadIdx.x;
    int w    = tid >> 6, lane = tid & 63;
    int j    = blockIdx.x * 8 + w;
    bool px  = probe32(lane);

    if (tid < 48) {
        float th = params[tid] * 0.5f;
        gs[2 * tid]     = __cosf(th);
        gs[2 * tid + 1] = __sinf(th);
    }
    __syncthreads();

    // basis state e_j
    float re[4], im[4];
#pragma unroll
    for (int k = 0; k < 4; ++k) {
        re[k] = ((j >> 6) == k && (j & 63) == lane) ? 1.f : 0.f;
        im[k] = 0.f;
    }

#define VQ(l, i) { const int jj = (l) * 24 + (i) * 3;                       \
                   apply_ry<7 - (i)>(re, im, lane, px, gs[2*jj],   gs[2*jj+1]); \
                   apply_rz<7 - (i)>(re, im, lane,     gs[2*jj+2], gs[2*jj+3]); }
#define CN(i)    apply_cnot<7 - (i), 6 - (i)>(re, im, lane, px);
#define RXQ(l,i) { const int jj = (l) * 24 + (i) * 3 + 2;                   \
                   apply_rx<7 - (i)>(re, im, lane, px, gs[2*jj], gs[2*jj+1]); }
#define LAYER(l) \
    VQ(l,0) CN(0) VQ(l,1) CN(1) VQ(l,2) CN(2) VQ(l,3) CN(3) \
    VQ(l,4) CN(4) VQ(l,5) CN(5) VQ(l,6) CN(6) VQ(l,7)       \
    RXQ(l,0) RXQ(l,1) RXQ(l,2) RXQ(l,3) RXQ(l,4) RXQ(l,5) RXQ(l,6) RXQ(l,7)

    LAYER(0)
    LAYER(1)
#undef LAYER
#undef RXQ
#undef CN
#undef VQ

    // fold encoding phase (-i)^pc(j) into the column (sel wave-uniform)
    int sel = __popc((u32)j) & 3;
#pragma unroll
    for (int k = 0; k < 4; ++k) {
        int idx = k * 64 + lane;
        float g, h;
        if      (sel == 0) { g =  re[k]; h =  im[k]; }
        else if (sel == 1) { g =  im[k]; h = -re[k]; }
        else if (sel == 2) { g = -re[k]; h = -im[k]; }
        else               { g = -im[k]; h =  re[k]; }
        Lg[w][idx] = (f16)g;
        Lh[w][idx] = (f16)h;
    }
    __syncthreads();

    // coalesced writeout: thread t<256 -> Bg[idx=t], t>=256 -> Bh[idx=t-256]
    {
        int idx  = tid & 255;
        bool ish = tid >= 256;
        const f16* src = ish ? &Lh[0][0] : &Lg[0][0];
        f16x8 v;
#pragma unroll
        for (int wv = 0; wv < 8; ++wv) v[wv] = src[wv * 256 + idx];
        f16* dst = ish ? Bh : Bg;
        int kb = blockIdx.x >> 2, joff = (blockIdx.x & 3) * 8;
        *reinterpret_cast<f16x8*>(&dst[(kb * 256 + idx) * 32 + joff]) = v;
    }
}

// ---------- kernel 2: real-A encode + 2 real GEMMs + Walsh readout ----------
// P[b,j] = prod of magnitude factors (natural sign, NO phase) -> one real
// A-operand; C_re = P.G^T, C_im = P.H^T: 2 MFMAs/tile instead of 4.

__global__ __launch_bounds__(512, 2) void qa_gemm(
    const float* __restrict__ x,
    const f16* __restrict__ Bg, const f16* __restrict__ Bh,
    float* __restrict__ out, int batch)
{
    __shared__ __align__(16) f16 Ap[32 * 256];
    __shared__ float zb[4][32][8];

    int tid  = threadIdx.x;
    int w    = tid >> 6, lane = tid & 63;
    int rg   = w >> 2,   cg   = w & 3;
    int b0   = blockIdx.x * 32;
    if (b0 >= batch) return;

    // ---- encode rows w*4 .. w*4+3: P = magnitude product only ----
#pragma unroll
    for (int e = 0; e < 4; ++e) {
        int rl = w * 4 + e;
        const float* xb = x + (b0 + rl) * 8;
        float4 xlo = *(const float4*)xb;
        float4 xhi = *(const float4*)(xb + 4);
        float c_[8], s_[8];
        __sincosf(xlo.x * 0.5f, &s_[0], &c_[0]);
        __sincosf(xlo.y * 0.5f, &s_[1], &c_[1]);
        __sincosf(xlo.z * 0.5f, &s_[2], &c_[2]);
        __sincosf(xlo.w * 0.5f, &s_[3], &c_[3]);
        __sincosf(xhi.x * 0.5f, &s_[4], &c_[4]);
        __sincosf(xhi.y * 0.5f, &s_[5], &c_[5]);
        __sincosf(xhi.z * 0.5f, &s_[6], &c_[6]);
        __sincosf(xhi.w * 0.5f, &s_[7], &c_[7]);

        float m6;
        m6  = ((lane >> 5) & 1) ? s_[2] : c_[2];
        m6 *= ((lane >> 4) & 1) ? s_[3] : c_[3];
        m6 *= ((lane >> 3) & 1) ? s_[4] : c_[4];
        m6 *= ((lane >> 2) & 1) ? s_[5] : c_[5];
        m6 *= ((lane >> 1) & 1) ? s_[6] : c_[6];
        m6 *= ( lane       & 1) ? s_[7] : c_[7];
        float kf[4] = { c_[0] * c_[1], c_[0] * s_[1], s_[0] * c_[1], s_[0] * s_[1] };
        int sw = (rl & 7) << 3;
#pragma unroll
        for (int k = 0; k < 4; ++k) {
            int j  = k * 64 + lane;
            int hi = rl * 256 + (j ^ sw);
            Ap[hi] = (f16)(m6 * kf[k]);
        }
    }
    __syncthreads();

    // ---- K loop: 8 steps of 32, 8 MFMAs each (2 per col-tile) ----
    f32x4 accR[4], accI[4];
#pragma unroll
    for (int t = 0; t < 4; ++t) { accR[t] = (f32x4)0.f; accI[t] = (f32x4)0.f; }

    int colbase = cg * 64 + (lane & 15);
    int arow    = rg * 16 + (lane & 15);
    int kg      = lane >> 4;
    const f16x8* B8g = reinterpret_cast<const f16x8*>(Bg);
    const f16x8* B8h = reinterpret_cast<const f16x8*>(Bh);

#pragma unroll
    for (int kb = 0; kb < 8; ++kb) {
        int afi = arow * 32 + ((kb * 4 + kg) ^ (arow & 7));
        f16x8 ap = *reinterpret_cast<const f16x8*>(&Ap[afi * 8]);
#pragma unroll
        for (int t = 0; t < 4; ++t) {
            int idx = colbase + t * 16;
            int bo  = (kb * 256 + idx) * 4 + kg;
            f16x8 bg = B8g[bo];
            f16x8 bh = B8h[bo];
            accR[t] = __builtin_amdgcn_mfma_f32_16x16x32_f16(ap, bg, accR[t], 0, 0, 0);
            accI[t] = __builtin_amdgcn_mfma_f32_16x16x32_f16(ap, bh, accI[t], 0, 0, 0);
        }
    }

    // ---- Walsh epilogue: Z_q = sum_idx (1-2*bit_{7-q}(idx)) * |c|^2 ----
    float z[4][8];
#pragma unroll
    for (int r = 0; r < 4; ++r)
#pragma unroll
        for (int q = 0; q < 8; ++q) z[r][q] = 0.f;

#pragma unroll
    for (int t = 0; t < 4; ++t) {
        int idx = colbase + t * 16;
#pragma unroll
        for (int r = 0; r < 4; ++r) {
            float cr = accR[t][r], ci = accI[t][r];
            float p = fmaf(cr, cr, ci * ci);
#pragma unroll
            for (int q = 0; q < 8; ++q)
                z[r][q] += ((idx >> (7 - q)) & 1) ? -p : p;
        }
    }

    // reduce over the 16 column-lanes (lane bits 0..3)
#pragma unroll
    for (int r = 0; r < 4; ++r)
#pragma unroll
        for (int q = 0; q < 8; ++q) {
            z[r][q] += lshfl<0>(z[r][q], false);
            z[r][q] += lshfl<1>(z[r][q], false);
            z[r][q] += lshfl<2>(z[r][q], false);
            z[r][q] += lshfl<3>(z[r][q], false);
        }

    // D-layout rows: row = rg*16 + (lane>>4)*4 + r
    if ((lane & 15) < 8) {
        int q = lane & 7;
#pragma unroll
        for (int r = 0; r < 4; ++r)
            zb[cg][rg * 16 + (lane >> 4) * 4 + r][q] = z[r][q];
    }
    __syncthreads();

    if (tid < 256) {
        int row = tid >> 3, q = tid & 7;
        float v = zb[0][row][q] + zb[1][row][q] + zb[2][row][q] + zb[3][row][q];
        out[(b0 + row) * 8 + q] = v;
    }
}

extern "C" void kernel_launch(void* const* d_in, const int* in_sizes, int n_in,
                              void* d_out, int out_size, void* d_ws, size_t ws_size,
                              hipStream_t stream) {
    const float* x      = (const float*)d_in[0];   // (BATCH, 8)
    const float* params = (const float*)d_in[1];   // (2, 8, 3) = 48
    float* out = (float*)d_out;

    f16* Bg = (f16*)d_ws;               // 128 KB (phase-folded "real" matrix)
    f16* Bh = Bg + 65536;               // 128 KB (phase-folded "imag" matrix)

    int batch = in_sizes[0] / 8;

    qa_genU<<<32, 512, 0, stream>>>(params, Bg, Bh);

    int blocks = (batch + 31) / 32;
    qa_gemm<<<blocks, 512, 0, stream>>>(x, Bg, Bh, out, batch);
}

// Round 22
// 22.233 us; speedup vs baseline: 3.1574x; 1.1389x over previous
//
#include <hip/hip_runtime.h>

#define DEV __device__ __forceinline__

typedef unsigned u32;
typedef u32 u32x2 __attribute__((ext_vector_type(2)));
typedef _Float16 f16;
typedef f16   f16x8 __attribute__((ext_vector_type(8)));
typedef float f32x4 __attribute__((ext_vector_type(4)));

// ---------- DPP helpers ----------
template<int CTRL>
DEV int dpp_full(int src) {
    return __builtin_amdgcn_update_dpp(src, src, CTRL, 0xF, 0xF, false);
}
template<int CTRL, int RM, int BM>
DEV int dpp_masked(int old, int src) {
    return __builtin_amdgcn_update_dpp(old, src, CTRL, RM, BM, false);
}

// ---------- cross-lane xor-shuffle (r7-proven mix) ----------
template<int B>
DEV float lshfl(float x, bool px) {
    int xi = __float_as_int(x);
    if constexpr (B == 0) {
        return __int_as_float(dpp_full<0xB1>(xi));          // xor1
    } else if constexpr (B == 1) {
        return __int_as_float(dpp_full<0x4E>(xi));          // xor2
    } else if constexpr (B == 2) {
        return __int_as_float(__builtin_amdgcn_ds_swizzle(xi, 0x101F)); // xor4
    } else if constexpr (B == 3) {
        return __int_as_float(dpp_full<0x128>(xi));         // xor8
    } else if constexpr (B == 4) {
        return __int_as_float(__builtin_amdgcn_ds_swizzle(xi, 0x401F)); // xor16
    } else {
        u32x2 r = __builtin_amdgcn_permlane32_swap((u32)xi, (u32)xi, false, false);
        return __int_as_float((int)(px ? r.x : r.y));
    }
}

DEV bool probe32(int lane) {
    u32 p = (u32)((lane >> 5) & 1);
    u32x2 r = __builtin_amdgcn_permlane32_swap(p, p, false, false);
    return r.x == (p ^ 1u);
}

// ---------- complex pair primitives (fp32) ----------
DEV void rx_pair(float& r0, float& i0, float& r1, float& i1, float c, float s) {
    float nr0 = fmaf(c, r0,  s * i1);
    float ni0 = fmaf(c, i0, -s * r1);
    float nr1 = fmaf(c, r1,  s * i0);
    float ni1 = fmaf(c, i1, -s * r0);
    r0 = nr0; i0 = ni0; r1 = nr1; i1 = ni1;
}
DEV void ry_pair(float& r0, float& i0, float& r1, float& i1, float c, float s) {
    float nr0 = fmaf(c, r0, -s * r1);
    float ni0 = fmaf(c, i0, -s * i1);
    float nr1 = fmaf(c, r1,  s * r0);
    float ni1 = fmaf(c, i1,  s * i0);
    r0 = nr0; i0 = ni0; r1 = nr1; i1 = ni1;
}
DEV void rz_amp(float& r, float& i, float c, float ss) {
    float nr = fmaf(c, r, -ss * i);
    float ni = fmaf(c, i,  ss * r);
    r = nr; i = ni;
}

// ---------- gates on flat-index bit B (B = 7 - qubit), r7-verified ----------
template<int B>
DEV void apply_rx(float (&re)[4], float (&im)[4], int lane, bool px, float c, float s) {
    if constexpr (B == 7) {
        rx_pair(re[0], im[0], re[2], im[2], c, s);
        rx_pair(re[1], im[1], re[3], im[3], c, s);
    } else if constexpr (B == 6) {
        rx_pair(re[0], im[0], re[1], im[1], c, s);
        rx_pair(re[2], im[2], re[3], im[3], c, s);
    } else {
#pragma unroll
        for (int k = 0; k < 4; ++k) {
            float pr = lshfl<B>(re[k], px);
            float pi = lshfl<B>(im[k], px);
            re[k] = fmaf(c, re[k],  s * pi);
            im[k] = fmaf(c, im[k], -s * pr);
        }
    }
}
template<int B>
DEV void apply_ry(float (&re)[4], float (&im)[4], int lane, bool px, float c, float s) {
    if constexpr (B == 7) {
        ry_pair(re[0], im[0], re[2], im[2], c, s);
        ry_pair(re[1], im[1], re[3], im[3], c, s);
    } else if constexpr (B == 6) {
        ry_pair(re[0], im[0], re[1], im[1], c, s);
        ry_pair(re[2], im[2], re[3], im[3], c, s);
    } else {
        float ssel = ((lane >> B) & 1) ? s : -s;
#pragma unroll
        for (int k = 0; k < 4; ++k) {
            float pr = lshfl<B>(re[k], px);
            float pi = lshfl<B>(im[k], px);
            re[k] = fmaf(c, re[k], ssel * pr);
            im[k] = fmaf(c, im[k], ssel * pi);
        }
    }
}
template<int B>
DEV void apply_rz(float (&re)[4], float (&im)[4], int lane, float c, float s) {
    if constexpr (B == 7) {
        rz_amp(re[0], im[0], c, -s); rz_amp(re[1], im[1], c, -s);
        rz_amp(re[2], im[2], c,  s); rz_amp(re[3], im[3], c,  s);
    } else if constexpr (B == 6) {
        rz_amp(re[0], im[0], c, -s); rz_amp(re[1], im[1], c,  s);
        rz_amp(re[2], im[2], c, -s); rz_amp(re[3], im[3], c,  s);
    } else {
        float ss = ((lane >> B) & 1) ? s : -s;
#pragma unroll
        for (int k = 0; k < 4; ++k) rz_amp(re[k], im[k], c, ss);
    }
}
template<int BC, int BT>
DEV void apply_cnot(float (&re)[4], float (&im)[4], int lane, bool px) {
    if constexpr (BC == 7 && BT == 6) {
        float tr = re[2], ti = im[2];
        re[2] = re[3]; im[2] = im[3];
        re[3] = tr;    im[3] = ti;
    } else if constexpr (BC == 6) {
        re[1] = lshfl<5>(re[1], px); im[1] = lshfl<5>(im[1], px);
        re[3] = lshfl<5>(re[3], px); im[3] = lshfl<5>(im[3], px);
    } else if constexpr (BC == 5 && BT == 4) {
        bool ctrl = (lane >> 5) & 1;
#pragma unroll
        for (int k = 0; k < 4; ++k) {
            float pr = lshfl<4>(re[k], px);
            float pi = lshfl<4>(im[k], px);
            re[k] = ctrl ? pr : re[k];
            im[k] = ctrl ? pi : im[k];
        }
    } else if constexpr (BC == 4 && BT == 3) {
#pragma unroll
        for (int k = 0; k < 4; ++k) {
            int r = __float_as_int(re[k]), i = __float_as_int(im[k]);
            re[k] = __int_as_float(dpp_masked<0x128, 0xA, 0xF>(r, r));
            im[k] = __int_as_float(dpp_masked<0x128, 0xA, 0xF>(i, i));
        }
    } else if constexpr (BC == 3 && BT == 2) {
#pragma unroll
        for (int k = 0; k < 4; ++k) {
            int r = __float_as_int(re[k]), i = __float_as_int(im[k]);
            int tr = dpp_full<0x1B>(r), ti = dpp_full<0x1B>(i);
            re[k] = __int_as_float(dpp_masked<0x141, 0xF, 0xC>(r, tr));
            im[k] = __int_as_float(dpp_masked<0x141, 0xF, 0xC>(i, ti));
        }
    } else if constexpr (BC == 2 && BT == 1) {
#pragma unroll
        for (int k = 0; k < 4; ++k) {
            int r = __float_as_int(re[k]), i = __float_as_int(im[k]);
            re[k] = __int_as_float(dpp_masked<0x4E, 0xF, 0xA>(r, r));
            im[k] = __int_as_float(dpp_masked<0x4E, 0xF, 0xA>(i, i));
        }
    } else {
#pragma unroll
        for (int k = 0; k < 4; ++k) {
            re[k] = __int_as_float(dpp_full<0xB4>(__float_as_int(re[k])));
            im[k] = __int_as_float(dpp_full<0xB4>(__float_as_int(im[k])));
        }
    }
}

// ---------- kernel 1: build G,H (phase-folded U) — r21-verified, unchanged ----------

__global__ __launch_bounds__(512) void qa_genU(
    const float* __restrict__ params, f16* __restrict__ Bg, f16* __restrict__ Bh)
{
    __shared__ float gs[96];
    __shared__ f16 Lg[8][256];
    __shared__ f16 Lh[8][256];

    int tid  = threadIdx.x;
    int w    = tid >> 6, lane = tid & 63;
    int j    = blockIdx.x * 8 + w;
    bool px  = probe32(lane);

    if (tid < 48) {
        float th = params[tid] * 0.5f;
        gs[2 * tid]     = __cosf(th);
        gs[2 * tid + 1] = __sinf(th);
    }
    __syncthreads();

    float re[4], im[4];
#pragma unroll
    for (int k = 0; k < 4; ++k) {
        re[k] = ((j >> 6) == k && (j & 63) == lane) ? 1.f : 0.f;
        im[k] = 0.f;
    }

#define VQ(l, i) { const int jj = (l) * 24 + (i) * 3;                       \
                   apply_ry<7 - (i)>(re, im, lane, px, gs[2*jj],   gs[2*jj+1]); \
                   apply_rz<7 - (i)>(re, im, lane,     gs[2*jj+2], gs[2*jj+3]); }
#define CN(i)    apply_cnot<7 - (i), 6 - (i)>(re, im, lane, px);
#define RXQ(l,i) { const int jj = (l) * 24 + (i) * 3 + 2;                   \
                   apply_rx<7 - (i)>(re, im, lane, px, gs[2*jj], gs[2*jj+1]); }
#define LAYER(l) \
    VQ(l,0) CN(0) VQ(l,1) CN(1) VQ(l,2) CN(2) VQ(l,3) CN(3) \
    VQ(l,4) CN(4) VQ(l,5) CN(5) VQ(l,6) CN(6) VQ(l,7)       \
    RXQ(l,0) RXQ(l,1) RXQ(l,2) RXQ(l,3) RXQ(l,4) RXQ(l,5) RXQ(l,6) RXQ(l,7)

    LAYER(0)
    LAYER(1)
#undef LAYER
#undef RXQ
#undef CN
#undef VQ

    // fold encoding phase (-i)^pc(j) into the column (sel wave-uniform)
    int sel = __popc((u32)j) & 3;
#pragma unroll
    for (int k = 0; k < 4; ++k) {
        int idx = k * 64 + lane;
        float g, h;
        if      (sel == 0) { g =  re[k]; h =  im[k]; }
        else if (sel == 1) { g =  im[k]; h = -re[k]; }
        else if (sel == 2) { g = -re[k]; h = -im[k]; }
        else               { g = -im[k]; h =  re[k]; }
        Lg[w][idx] = (f16)g;
        Lh[w][idx] = (f16)h;
    }
    __syncthreads();

    {
        int idx  = tid & 255;
        bool ish = tid >= 256;
        const f16* src = ish ? &Lh[0][0] : &Lg[0][0];
        f16x8 v;
#pragma unroll
        for (int wv = 0; wv < 8; ++wv) v[wv] = src[wv * 256 + idx];
        f16* dst = ish ? Bh : Bg;
        int kb = blockIdx.x >> 2, joff = (blockIdx.x & 3) * 8;
        *reinterpret_cast<f16x8*>(&dst[(kb * 256 + idx) * 32 + joff]) = v;
    }
}

// ---------- kernel 2: 16 rows/block (2 blocks/CU), separable Walsh epilogue ----------
// Wave w owns col-group w: idx = w*32 + t*16 + L, L = lane&15, t in {0,1}.
// idx bits: [3:0]=L, [4]=t, [7:5]=w  ->  Z_q signs separate per bit group.

__global__ __launch_bounds__(512, 4) void qa_gemm(
    const float* __restrict__ x,
    const f16* __restrict__ Bg, const f16* __restrict__ Bh,
    float* __restrict__ out, int batch)
{
    __shared__ __align__(16) f16 Ap[16 * 256];
    __shared__ float zb[8][16][8];

    int tid  = threadIdx.x;
    int w    = tid >> 6, lane = tid & 63;
    int b0   = blockIdx.x * 16;
    if (b0 >= batch) return;

    // ---- encode rows w*2, w*2+1: P = magnitude product (no phase) ----
#pragma unroll
    for (int e = 0; e < 2; ++e) {
        int rl = w * 2 + e;
        int bb = b0 + rl; if (bb >= batch) bb = batch - 1;
        const float* xb = x + bb * 8;
        float4 xlo = *(const float4*)xb;
        float4 xhi = *(const float4*)(xb + 4);
        float c_[8], s_[8];
        __sincosf(xlo.x * 0.5f, &s_[0], &c_[0]);
        __sincosf(xlo.y * 0.5f, &s_[1], &c_[1]);
        __sincosf(xlo.z * 0.5f, &s_[2], &c_[2]);
        __sincosf(xlo.w * 0.5f, &s_[3], &c_[3]);
        __sincosf(xhi.x * 0.5f, &s_[4], &c_[4]);
        __sincosf(xhi.y * 0.5f, &s_[5], &c_[5]);
        __sincosf(xhi.z * 0.5f, &s_[6], &c_[6]);
        __sincosf(xhi.w * 0.5f, &s_[7], &c_[7]);

        float m6;
        m6  = ((lane >> 5) & 1) ? s_[2] : c_[2];
        m6 *= ((lane >> 4) & 1) ? s_[3] : c_[3];
        m6 *= ((lane >> 3) & 1) ? s_[4] : c_[4];
        m6 *= ((lane >> 2) & 1) ? s_[5] : c_[5];
        m6 *= ((lane >> 1) & 1) ? s_[6] : c_[6];
        m6 *= ( lane       & 1) ? s_[7] : c_[7];
        float kf[4] = { c_[0] * c_[1], c_[0] * s_[1], s_[0] * c_[1], s_[0] * s_[1] };
        int sw = (rl & 7) << 3;
#pragma unroll
        for (int k = 0; k < 4; ++k) {
            int j  = k * 64 + lane;
            int hi = rl * 256 + (j ^ sw);
            Ap[hi] = (f16)(m6 * kf[k]);
        }
    }
    __syncthreads();

    // ---- K loop: 8 steps of 32, 4 MFMAs each (2 per col-tile) ----
    f32x4 accR[2], accI[2];
#pragma unroll
    for (int t = 0; t < 2; ++t) { accR[t] = (f32x4)0.f; accI[t] = (f32x4)0.f; }

    int L       = lane & 15;
    int colbase = w * 32 + L;
    int arow    = L;               // A row = batch row within 16
    int kg      = lane >> 4;
    const f16x8* B8g = reinterpret_cast<const f16x8*>(Bg);
    const f16x8* B8h = reinterpret_cast<const f16x8*>(Bh);

#pragma unroll
    for (int kb = 0; kb < 8; ++kb) {
        int afi = arow * 32 + ((kb * 4 + kg) ^ (arow & 7));
        f16x8 ap = *reinterpret_cast<const f16x8*>(&Ap[afi * 8]);
#pragma unroll
        for (int t = 0; t < 2; ++t) {
            int idx = colbase + t * 16;
            int bo  = (kb * 256 + idx) * 4 + kg;
            f16x8 bg = B8g[bo];
            f16x8 bh = B8h[bo];
            accR[t] = __builtin_amdgcn_mfma_f32_16x16x32_f16(ap, bg, accR[t], 0, 0, 0);
            accI[t] = __builtin_amdgcn_mfma_f32_16x16x32_f16(ap, bh, accI[t], 0, 0, 0);
        }
    }

    // ---- separable Walsh epilogue ----
    // D layout: batch row = (lane>>4)*4 + r, idx-low4 = L (m89-verified).
    bool wr = (L < 8);
#pragma unroll
    for (int r = 0; r < 4; ++r) {
        float p0 = fmaf(accR[0][r], accR[0][r], accI[0][r] * accI[0][r]);
        float p1 = fmaf(accR[1][r], accR[1][r], accI[1][r] * accI[1][r]);
        float S = p0 + p1;      // q3 bit = t
        float T = p0 - p1;

        // pruned WH over lane bits 0..3 on S
        float P;
        P = lshfl<0>(S, false); float w0d = S - P; S += P;
        P = lshfl<1>(S, false); float w1d = S - P; S += P;
        P = lshfl<2>(S, false); float w2d = S - P; S += P;
        P = lshfl<3>(S, false); float w3d = S - P; S += P;   // S = full sum
        w0d += lshfl<1>(w0d, false); w0d += lshfl<2>(w0d, false); w0d += lshfl<3>(w0d, false);
        w1d += lshfl<2>(w1d, false); w1d += lshfl<3>(w1d, false);
        w2d += lshfl<3>(w2d, false);

        // T full reduce over lane bits 0..3
        T += lshfl<0>(T, false); T += lshfl<1>(T, false);
        T += lshfl<2>(T, false); T += lshfl<3>(T, false);

        if (wr) {
            // writer lane L writes q = L; sign fixups are compile-time per q
            float val = (L == 0) ? ((w & 4) ? -S : S)
                      : (L == 1) ? ((w & 2) ? -S : S)
                      : (L == 2) ? ((w & 1) ? -S : S)
                      : (L == 3) ? T
                      : (L == 4) ? w3d          // L bit3 = 0 -> + sign
                      : (L == 5) ? -w2d         // L=5: bit2=1 -> negate
                      : (L == 6) ? -w1d         // L=6: bit1=1 -> negate
                      :            -w0d;        // L=7: bit0=1 -> negate
            zb[w][(lane >> 4) * 4 + r][L] = val;
        }
    }
    __syncthreads();

    // ---- final: sum 8 col-groups, write 16 rows x 8 q ----
    if (tid < 128) {
        int row = tid >> 3, q = tid & 7;
        float v = 0.f;
#pragma unroll
        for (int g = 0; g < 8; ++g) v += zb[g][row][q];
        if (b0 + row < batch) out[(b0 + row) * 8 + q] = v;
    }
}

extern "C" void kernel_launch(void* const* d_in, const int* in_sizes, int n_in,
                              void* d_out, int out_size, void* d_ws, size_t ws_size,
                              hipStream_t stream) {
    const float* x      = (const float*)d_in[0];   // (BATCH, 8)
    const float* params = (const float*)d_in[1];   // (2, 8, 3) = 48
    float* out = (float*)d_out;

    f16* Bg = (f16*)d_ws;               // 128 KB (phase-folded "real" matrix)
    f16* Bh = Bg + 65536;               // 128 KB (phase-folded "imag" matrix)

    int batch = in_sizes[0] / 8;

    qa_genU<<<32, 512, 0, stream>>>(params, Bg, Bh);

    int blocks = (batch + 15) / 16;
    qa_gemm<<<blocks, 512, 0, stream>>>(x, Bg, Bh, out, batch);
}

// Round 23
// 20.626 us; speedup vs baseline: 3.4035x; 1.0779x over previous
//
#include <hip/hip_runtime.h>

#define DEV __device__ __forceinline__

typedef unsigned u32;
typedef u32 u32x2 __attribute__((ext_vector_type(2)));
typedef _Float16 f16;
typedef f16   f16x8 __attribute__((ext_vector_type(8)));
typedef float f32x4 __attribute__((ext_vector_type(4)));

// ---------- DPP helpers ----------
template<int CTRL>
DEV int dpp_full(int src) {
    return __builtin_amdgcn_update_dpp(src, src, CTRL, 0xF, 0xF, false);
}
template<int CTRL, int RM, int BM>
DEV int dpp_masked(int old, int src) {
    return __builtin_amdgcn_update_dpp(old, src, CTRL, RM, BM, false);
}

// ---------- cross-lane xor-shuffle (r7-proven mix) ----------
template<int B>
DEV float lshfl(float x, bool px) {
    int xi = __float_as_int(x);
    if constexpr (B == 0) {
        return __int_as_float(dpp_full<0xB1>(xi));          // xor1
    } else if constexpr (B == 1) {
        return __int_as_float(dpp_full<0x4E>(xi));          // xor2
    } else if constexpr (B == 2) {
        return __int_as_float(__builtin_amdgcn_ds_swizzle(xi, 0x101F)); // xor4
    } else if constexpr (B == 3) {
        return __int_as_float(dpp_full<0x128>(xi));         // xor8
    } else if constexpr (B == 4) {
        return __int_as_float(__builtin_amdgcn_ds_swizzle(xi, 0x401F)); // xor16
    } else {
        u32x2 r = __builtin_amdgcn_permlane32_swap((u32)xi, (u32)xi, false, false);
        return __int_as_float((int)(px ? r.x : r.y));
    }
}

DEV bool probe32(int lane) {
    u32 p = (u32)((lane >> 5) & 1);
    u32x2 r = __builtin_amdgcn_permlane32_swap(p, p, false, false);
    return r.x == (p ^ 1u);
}

// ---------- complex pair primitives (fp32) ----------
DEV void rx_pair(float& r0, float& i0, float& r1, float& i1, float c, float s) {
    float nr0 = fmaf(c, r0,  s * i1);
    float ni0 = fmaf(c, i0, -s * r1);
    float nr1 = fmaf(c, r1,  s * i0);
    float ni1 = fmaf(c, i1, -s * r0);
    r0 = nr0; i0 = ni0; r1 = nr1; i1 = ni1;
}
DEV void ry_pair(float& r0, float& i0, float& r1, float& i1, float c, float s) {
    float nr0 = fmaf(c, r0, -s * r1);
    float ni0 = fmaf(c, i0, -s * i1);
    float nr1 = fmaf(c, r1,  s * r0);
    float ni1 = fmaf(c, i1,  s * i0);
    r0 = nr0; i0 = ni0; r1 = nr1; i1 = ni1;
}
DEV void rz_amp(float& r, float& i, float c, float ss) {
    float nr = fmaf(c, r, -ss * i);
    float ni = fmaf(c, i,  ss * r);
    r = nr; i = ni;
}

// ---------- gates on flat-index bit B (B = 7 - qubit), r7-verified ----------
template<int B>
DEV void apply_rx(float (&re)[4], float (&im)[4], int lane, bool px, float c, float s) {
    if constexpr (B == 7) {
        rx_pair(re[0], im[0], re[2], im[2], c, s);
        rx_pair(re[1], im[1], re[3], im[3], c, s);
    } else if constexpr (B == 6) {
        rx_pair(re[0], im[0], re[1], im[1], c, s);
        rx_pair(re[2], im[2], re[3], im[3], c, s);
    } else {
#pragma unroll
        for (int k = 0; k < 4; ++k) {
            float pr = lshfl<B>(re[k], px);
            float pi = lshfl<B>(im[k], px);
            re[k] = fmaf(c, re[k],  s * pi);
            im[k] = fmaf(c, im[k], -s * pr);
        }
    }
}
template<int B>
DEV void apply_ry(float (&re)[4], float (&im)[4], int lane, bool px, float c, float s) {
    if constexpr (B == 7) {
        ry_pair(re[0], im[0], re[2], im[2], c, s);
        ry_pair(re[1], im[1], re[3], im[3], c, s);
    } else if constexpr (B == 6) {
        ry_pair(re[0], im[0], re[1], im[1], c, s);
        ry_pair(re[2], im[2], re[3], im[3], c, s);
    } else {
        float ssel = ((lane >> B) & 1) ? s : -s;
#pragma unroll
        for (int k = 0; k < 4; ++k) {
            float pr = lshfl<B>(re[k], px);
            float pi = lshfl<B>(im[k], px);
            re[k] = fmaf(c, re[k], ssel * pr);
            im[k] = fmaf(c, im[k], ssel * pi);
        }
    }
}
template<int B>
DEV void apply_rz(float (&re)[4], float (&im)[4], int lane, float c, float s) {
    if constexpr (B == 7) {
        rz_amp(re[0], im[0], c, -s); rz_amp(re[1], im[1], c, -s);
        rz_amp(re[2], im[2], c,  s); rz_amp(re[3], im[3], c,  s);
    } else if constexpr (B == 6) {
        rz_amp(re[0], im[0], c, -s); rz_amp(re[1], im[1], c,  s);
        rz_amp(re[2], im[2], c, -s); rz_amp(re[3], im[3], c,  s);
    } else {
        float ss = ((lane >> B) & 1) ? s : -s;
#pragma unroll
        for (int k = 0; k < 4; ++k) rz_amp(re[k], im[k], c, ss);
    }
}
template<int BC, int BT>
DEV void apply_cnot(float (&re)[4], float (&im)[4], int lane, bool px) {
    if constexpr (BC == 7 && BT == 6) {
        float tr = re[2], ti = im[2];
        re[2] = re[3]; im[2] = im[3];
        re[3] = tr;    im[3] = ti;
    } else if constexpr (BC == 6) {
        re[1] = lshfl<5>(re[1], px); im[1] = lshfl<5>(im[1], px);
        re[3] = lshfl<5>(re[3], px); im[3] = lshfl<5>(im[3], px);
    } else if constexpr (BC == 5 && BT == 4) {
        bool ctrl = (lane >> 5) & 1;
#pragma unroll
        for (int k = 0; k < 4; ++k) {
            float pr = lshfl<4>(re[k], px);
            float pi = lshfl<4>(im[k], px);
            re[k] = ctrl ? pr : re[k];
            im[k] = ctrl ? pi : im[k];
        }
    } else if constexpr (BC == 4 && BT == 3) {
#pragma unroll
        for (int k = 0; k < 4; ++k) {
            int r = __float_as_int(re[k]), i = __float_as_int(im[k]);
            re[k] = __int_as_float(dpp_masked<0x128, 0xA, 0xF>(r, r));
            im[k] = __int_as_float(dpp_masked<0x128, 0xA, 0xF>(i, i));
        }
    } else if constexpr (BC == 3 && BT == 2) {
#pragma unroll
        for (int k = 0; k < 4; ++k) {
            int r = __float_as_int(re[k]), i = __float_as_int(im[k]);
            int tr = dpp_full<0x1B>(r), ti = dpp_full<0x1B>(i);
            re[k] = __int_as_float(dpp_masked<0x141, 0xF, 0xC>(r, tr));
            im[k] = __int_as_float(dpp_masked<0x141, 0xF, 0xC>(i, ti));
        }
    } else if constexpr (BC == 2 && BT == 1) {
#pragma unroll
        for (int k = 0; k < 4; ++k) {
            int r = __float_as_int(re[k]), i = __float_as_int(im[k]);
            re[k] = __int_as_float(dpp_masked<0x4E, 0xF, 0xA>(r, r));
            im[k] = __int_as_float(dpp_masked<0x4E, 0xF, 0xA>(i, i));
        }
    } else {
#pragma unroll
        for (int k = 0; k < 4; ++k) {
            re[k] = __int_as_float(dpp_full<0xB4>(__float_as_int(re[k])));
            im[k] = __int_as_float(dpp_full<0xB4>(__float_as_int(im[k])));
        }
    }
}

// ---------- kernel 1: build G,H (phase-folded U) — r21-verified, unchanged ----------

__global__ __launch_bounds__(512) void qa_genU(
    const float* __restrict__ params, f16* __restrict__ Bg, f16* __restrict__ Bh)
{
    __shared__ float gs[96];
    __shared__ f16 Lg[8][256];
    __shared__ f16 Lh[8][256];

    int tid  = threadIdx.x;
    int w    = tid >> 6, lane = tid & 63;
    int j    = blockIdx.x * 8 + w;
    bool px  = probe32(lane);

    if (tid < 48) {
        float th = params[tid] * 0.5f;
        gs[2 * tid]     = __cosf(th);
        gs[2 * tid + 1] = __sinf(th);
    }
    __syncthreads();

    float re[4], im[4];
#pragma unroll
    for (int k = 0; k < 4; ++k) {
        re[k] = ((j >> 6) == k && (j & 63) == lane) ? 1.f : 0.f;
        im[k] = 0.f;
    }

#define VQ(l, i) { const int jj = (l) * 24 + (i) * 3;                       \
                   apply_ry<7 - (i)>(re, im, lane, px, gs[2*jj],   gs[2*jj+1]); \
                   apply_rz<7 - (i)>(re, im, lane,     gs[2*jj+2], gs[2*jj+3]); }
#define CN(i)    apply_cnot<7 - (i), 6 - (i)>(re, im, lane, px);
#define RXQ(l,i) { const int jj = (l) * 24 + (i) * 3 + 2;                   \
                   apply_rx<7 - (i)>(re, im, lane, px, gs[2*jj], gs[2*jj+1]); }
#define LAYER(l) \
    VQ(l,0) CN(0) VQ(l,1) CN(1) VQ(l,2) CN(2) VQ(l,3) CN(3) \
    VQ(l,4) CN(4) VQ(l,5) CN(5) VQ(l,6) CN(6) VQ(l,7)       \
    RXQ(l,0) RXQ(l,1) RXQ(l,2) RXQ(l,3) RXQ(l,4) RXQ(l,5) RXQ(l,6) RXQ(l,7)

    LAYER(0)
    LAYER(1)
#undef LAYER
#undef RXQ
#undef CN
#undef VQ

    // fold encoding phase (-i)^pc(j) into the column (sel wave-uniform)
    int sel = __popc((u32)j) & 3;
#pragma unroll
    for (int k = 0; k < 4; ++k) {
        int idx = k * 64 + lane;
        float g, h;
        if      (sel == 0) { g =  re[k]; h =  im[k]; }
        else if (sel == 1) { g =  im[k]; h = -re[k]; }
        else if (sel == 2) { g = -re[k]; h = -im[k]; }
        else               { g = -im[k]; h =  re[k]; }
        Lg[w][idx] = (f16)g;
        Lh[w][idx] = (f16)h;
    }
    __syncthreads();

    {
        int idx  = tid & 255;
        bool ish = tid >= 256;
        const f16* src = ish ? &Lh[0][0] : &Lg[0][0];
        f16x8 v;
#pragma unroll
        for (int wv = 0; wv < 8; ++wv) v[wv] = src[wv * 256 + idx];
        f16* dst = ish ? Bh : Bg;
        int kb = blockIdx.x >> 2, joff = (blockIdx.x & 3) * 8;
        *reinterpret_cast<f16x8*>(&dst[(kb * 256 + idx) * 32 + joff]) = v;
    }
}

// ---------- kernel 2: 32 rows/block, 16 waves (1024 thr), 2x B-reuse ----------
// Wave w owns col-tile w: idx = w*16 + L, L = lane&15.
// idx bits: [3:0]=L, [7:4]=w  ->  q0..3 signs wave-uniform, q4..7 via lane WH.
// Per kb-step: 2 A ds_reads (row-tiles) + 2 B loads + 4 MFMAs (B reused 2x).

__global__ __launch_bounds__(1024, 4) void qa_gemm(
    const float* __restrict__ x,
    const f16* __restrict__ Bg, const f16* __restrict__ Bh,
    float* __restrict__ out, int batch)
{
    __shared__ __align__(16) f16 Ap[32 * 256];
    __shared__ float zb[16][32][8];

    int tid  = threadIdx.x;
    int w    = tid >> 6, lane = tid & 63;
    int b0   = blockIdx.x * 32;
    if (b0 >= batch) return;

    // ---- encode rows w*2, w*2+1: P = magnitude product (no phase) ----
#pragma unroll
    for (int e = 0; e < 2; ++e) {
        int rl = w * 2 + e;
        int bb = b0 + rl; if (bb >= batch) bb = batch - 1;
        const float* xb = x + bb * 8;
        float4 xlo = *(const float4*)xb;
        float4 xhi = *(const float4*)(xb + 4);
        float c_[8], s_[8];
        __sincosf(xlo.x * 0.5f, &s_[0], &c_[0]);
        __sincosf(xlo.y * 0.5f, &s_[1], &c_[1]);
        __sincosf(xlo.z * 0.5f, &s_[2], &c_[2]);
        __sincosf(xlo.w * 0.5f, &s_[3], &c_[3]);
        __sincosf(xhi.x * 0.5f, &s_[4], &c_[4]);
        __sincosf(xhi.y * 0.5f, &s_[5], &c_[5]);
        __sincosf(xhi.z * 0.5f, &s_[6], &c_[6]);
        __sincosf(xhi.w * 0.5f, &s_[7], &c_[7]);

        float m6;
        m6  = ((lane >> 5) & 1) ? s_[2] : c_[2];
        m6 *= ((lane >> 4) & 1) ? s_[3] : c_[3];
        m6 *= ((lane >> 3) & 1) ? s_[4] : c_[4];
        m6 *= ((lane >> 2) & 1) ? s_[5] : c_[5];
        m6 *= ((lane >> 1) & 1) ? s_[6] : c_[6];
        m6 *= ( lane       & 1) ? s_[7] : c_[7];
        float kf[4] = { c_[0] * c_[1], c_[0] * s_[1], s_[0] * c_[1], s_[0] * s_[1] };
        int sw = (rl & 7) << 3;
#pragma unroll
        for (int k = 0; k < 4; ++k) {
            int j  = k * 64 + lane;
            int hi = rl * 256 + (j ^ sw);
            Ap[hi] = (f16)(m6 * kf[k]);
        }
    }
    __syncthreads();

    // ---- K loop: 8 steps of 32; 2 B loads reused by 2 row-tiles ----
    f32x4 accR[2], accI[2];
#pragma unroll
    for (int rt = 0; rt < 2; ++rt) { accR[rt] = (f32x4)0.f; accI[rt] = (f32x4)0.f; }

    int L       = lane & 15;
    int colbase = w * 16 + L;
    int kg      = lane >> 4;
    const f16x8* B8g = reinterpret_cast<const f16x8*>(Bg);
    const f16x8* B8h = reinterpret_cast<const f16x8*>(Bh);

#pragma unroll
    for (int kb = 0; kb < 8; ++kb) {
        int bo  = (kb * 256 + colbase) * 4 + kg;
        f16x8 bg = B8g[bo];
        f16x8 bh = B8h[bo];
#pragma unroll
        for (int rt = 0; rt < 2; ++rt) {
            int arow = rt * 16 + L;
            int afi  = arow * 32 + ((kb * 4 + kg) ^ (arow & 7));
            f16x8 ap = *reinterpret_cast<const f16x8*>(&Ap[afi * 8]);
            accR[rt] = __builtin_amdgcn_mfma_f32_16x16x32_f16(ap, bg, accR[rt], 0, 0, 0);
            accI[rt] = __builtin_amdgcn_mfma_f32_16x16x32_f16(ap, bh, accI[rt], 0, 0, 0);
        }
    }

    // ---- separable Walsh epilogue ----
    // D layout: batch row = rt*16 + (lane>>4)*4 + r, idx-low4 = L (m89-verified).
    bool wr = (L < 8);
#pragma unroll
    for (int rt = 0; rt < 2; ++rt) {
#pragma unroll
        for (int r = 0; r < 4; ++r) {
            float S = fmaf(accR[rt][r], accR[rt][r], accI[rt][r] * accI[rt][r]);

            // pruned WH over lane bits 0..3
            float P;
            P = lshfl<0>(S, false); float w0d = S - P; S += P;
            P = lshfl<1>(S, false); float w1d = S - P; S += P;
            P = lshfl<2>(S, false); float w2d = S - P; S += P;
            P = lshfl<3>(S, false); float w3d = S - P; S += P;   // S = full sum
            w0d += lshfl<1>(w0d, false); w0d += lshfl<2>(w0d, false); w0d += lshfl<3>(w0d, false);
            w1d += lshfl<2>(w1d, false); w1d += lshfl<3>(w1d, false);
            w2d += lshfl<3>(w2d, false);

            if (wr) {
                // writer lane L writes q = L; q0..3 signs from w bits 3..0
                float val = (L == 0) ? ((w & 8) ? -S : S)
                          : (L == 1) ? ((w & 4) ? -S : S)
                          : (L == 2) ? ((w & 2) ? -S : S)
                          : (L == 3) ? ((w & 1) ? -S : S)
                          : (L == 4) ? w3d          // lane 4: bit3=0 -> +
                          : (L == 5) ? -w2d         // lane 5: bit2=1 -> -
                          : (L == 6) ? -w1d         // lane 6: bit1=1 -> -
                          :            -w0d;        // lane 7: bit0=1 -> -
                zb[w][rt * 16 + (lane >> 4) * 4 + r][L] = val;
            }
        }
    }
    __syncthreads();

    // ---- final: sum 16 col-groups, write 32 rows x 8 q ----
    if (tid < 256) {
        int row = tid >> 3, q = tid & 7;
        float v = 0.f;
#pragma unroll
        for (int g = 0; g < 16; ++g) v += zb[g][row][q];
        if (b0 + row < batch) out[(b0 + row) * 8 + q] = v;
    }
}

extern "C" void kernel_launch(void* const* d_in, const int* in_sizes, int n_in,
                              void* d_out, int out_size, void* d_ws, size_t ws_size,
                              hipStream_t stream) {
    const float* x      = (const float*)d_in[0];   // (BATCH, 8)
    const float* params = (const float*)d_in[1];   // (2, 8, 3) = 48
    float* out = (float*)d_out;

    f16* Bg = (f16*)d_ws;               // 128 KB (phase-folded "real" matrix)
    f16* Bh = Bg + 65536;               // 128 KB (phase-folded "imag" matrix)

    int batch = in_sizes[0] / 8;

    qa_genU<<<32, 512, 0, stream>>>(params, Bg, Bh);

    int blocks = (batch + 31) / 32;
    qa_gemm<<<blocks, 1024, 0, stream>>>(x, Bg, Bh, out, batch);
}